// Round 10
// baseline (389.404 us; speedup 1.0000x reference)
//
#include <hip/hip_runtime.h>
#include <cstdint>

// ---------------------------------------------------------------------------
// JanusCrossAttention: B=2,S=2048, Q_DIM=KV_DIM=2048, H=16, D=128, KVH=4
// I/O fp32; internals bf16 MFMA, fp32 accumulate.
//   1. cvt q_stream -> bf16 sb ; transpose weights -> bf16 [N][K]
//   2. xq = sb @ wqT  (triple-buffered counted-vmcnt GEMM, XCD-swizzled)
//   3. cvt kv_stream -> sb ; xkv = sb @ wkvT  (fused K|V, N=1024)
//   4. per-head RMSNorm xq, xk
//   5. repack K and V^T into MFMA-fragment-major tiles
//   6. flash attention: R6 structure FROZEN (best measured 69.9 us, VGPR 52).
//   7. out = ao @ woT (fp32 out)
// R9 lesson: dbuf GEMM gained only ~20 us because __syncthreads drains
// vmcnt(0) -> stage(it+1) gets ONE compute phase of cover while per-XCD
// working set (A 2MB + B 8MB) exceeds L2 -> L3/HBM-latency staging partially
// exposed at all 64 barriers. Fix (T4): triple buffer + prefetch distance 2 +
// s_waitcnt vmcnt(4) + raw s_barrier (stage it+2 stays in flight across the
// barrier) -> each stage gets ~2 compute phases (>= ~900cy HBM worst case).
// ---------------------------------------------------------------------------

using bf16 = __bf16;
using bf16x4 = __attribute__((ext_vector_type(4))) __bf16;
using bf16x8 = __attribute__((ext_vector_type(8))) __bf16;
using s16x4  = __attribute__((ext_vector_type(4))) short;
using f32x4  = __attribute__((ext_vector_type(4))) float;

#define SEQ 2048
#define NH 16
#define NKVH 4
#define HD 128

// finite "minus infinity": avoids inf-inf NaNs in the split-K defer-max path
#define NEG (-3.0e38f)

// 16x16x16 bf16 MFMA (K=16) — C layout of a prior 16x16 MFMA feeds B directly.
#if defined(__has_builtin)
#if __has_builtin(__builtin_amdgcn_mfma_f32_16x16x16bf16_1k)
#define HAVE_1K 1
#endif
#endif
__device__ __forceinline__ f32x4 mfma_16x16x16(bf16x4 a, bf16x4 b, f32x4 c) {
#ifdef HAVE_1K
    return __builtin_amdgcn_mfma_f32_16x16x16bf16_1k(
        __builtin_bit_cast(s16x4, a), __builtin_bit_cast(s16x4, b), c, 0, 0, 0);
#else
    f32x4 d;
    asm volatile("v_mfma_f32_16x16x16_bf16 %0, %1, %2, %3"
                 : "=v"(d) : "v"(a), "v"(b), "v"(c));
    return d;
#endif
}

// native exp2 (v_exp_f32)
__device__ __forceinline__ float fast_exp2(float x) {
#if defined(__has_builtin)
#if __has_builtin(__builtin_amdgcn_exp2f)
    return __builtin_amdgcn_exp2f(x);
#else
    return exp2f(x);
#endif
#else
    return exp2f(x);
#endif
}

// async global->LDS, 16B per lane. LDS dest must be wave-uniform base + lane*16.
__device__ __forceinline__ void load_lds16(const bf16* g, bf16* l) {
    __builtin_amdgcn_global_load_lds(
        (const __attribute__((address_space(1))) unsigned int*)g,
        (__attribute__((address_space(3))) unsigned int*)l, 16, 0, 0);
}

// ---------------------------------------------------------------------------
__global__ __launch_bounds__(256) void cvt_f32_bf16(const float* __restrict__ in,
                                                    bf16* __restrict__ out, int n8) {
    int i = blockIdx.x * 256 + threadIdx.x;
    if (i >= n8) return;
    const float4* p = (const float4*)in + (long)i * 2;
    float4 f0 = p[0], f1 = p[1];
    bf16x8 o = {(bf16)f0.x, (bf16)f0.y, (bf16)f0.z, (bf16)f0.w,
                (bf16)f1.x, (bf16)f1.y, (bf16)f1.z, (bf16)f1.w};
    *((bf16x8*)out + i) = o;
}

// 2D transpose + cast: in fp32 [R][C] -> out bf16 [C][R]
__global__ void transpose2d(const float* __restrict__ in, bf16* __restrict__ out,
                            int R, int C) {
    __shared__ bf16 tile[32][33];
    int x  = blockIdx.x * 32 + threadIdx.x;
    int y0 = blockIdx.y * 32 + threadIdx.y;
#pragma unroll
    for (int i = 0; i < 32; i += 8) {
        int y = y0 + i;
        if (y < R && x < C) tile[threadIdx.y + i][threadIdx.x] = (bf16)in[(long)y * C + x];
    }
    __syncthreads();
    int ox  = blockIdx.y * 32 + threadIdx.x;
    int oy0 = blockIdx.x * 32 + threadIdx.y;
#pragma unroll
    for (int i = 0; i < 32; i += 8) {
        int oy = oy0 + i;
        if (oy < C && ox < R) out[(long)oy * R + ox] = tile[threadIdx.x][threadIdx.y + i];
    }
}

// ---------------------------------------------------------------------------
// GEMM: C[M][N] = A[M][K] @ BT[N][K]^T, bf16 in, fp32 acc, CT out.
// 128x128 tile, BK=32, global_load_lds width-16 staging, TRIPLE-BUFFERED with
// counted vmcnt: stage k-tile it+2 at the top of iter it; end each iter with
// s_waitcnt vmcnt(4) (allow the 4 newest loads — stage it+2 — to remain in
// flight) + raw s_barrier + sched_barrier(0) (rule #18 pin). Each stage is
// covered by ~2 compute phases. Buffer it%3 is only rewritten by stage(it+3),
// one pinned barrier after its last ds_read (whose data the MFMAs already
// consumed -> lgkmcnt-waited). XCD swizzle (bid%8 -> XCD, R3-proven) keeps
// each XCD's A-chunk L2-resident; all call-site grids are %8==0.
template <typename CT>
__global__ __launch_bounds__(256) void gemm_bt(const bf16* __restrict__ A,
                                               const bf16* __restrict__ BT,
                                               CT* __restrict__ C,
                                               int M, int N, int K) {
    __shared__ bf16 As[3][128][32];
    __shared__ bf16 Bs[3][128][32];
    const int tid  = threadIdx.x;
    const int wave = tid >> 6, lane = tid & 63;
    const int nwg = gridDim.x * gridDim.y;
    const int bid = blockIdx.y * gridDim.x + blockIdx.x;
    const int swz = (bid & 7) * (nwg >> 3) + (bid >> 3);
    const int bx = swz % gridDim.x, by = swz / gridDim.x;
    const int m0 = by * 128, n0 = bx * 128;
    const int wm = (wave >> 1) * 64, wn = (wave & 1) * 64;
    const int lrow = lane & 15, quad = lane >> 4;
    const int lko = quad * 8;

    const bf16* ga0 = A  + (long)(m0 + (tid >> 2)) * K + (tid & 3) * 8;
    const bf16* ga1 = ga0 + 64L * K;
    const bf16* gb0 = BT + (long)(n0 + (tid >> 2)) * K + (tid & 3) * 8;
    const bf16* gb1 = gb0 + 64L * K;
    bf16* la0 = &As[0][0][0] + tid * 8;
    bf16* lb0 = &Bs[0][0][0] + tid * 8;

    // stage k-tile `it` into buffer it%3 (4 x 16B loads per thread)
    auto stg = [&](int it) {
        const int j = it % 3;
        const int k0 = it * 32;
        bf16* la = la0 + j * 4096;
        bf16* lb = lb0 + j * 4096;
        load_lds16(ga0 + k0, la);
        load_lds16(ga1 + k0, la + 2048);
        load_lds16(gb0 + k0, lb);
        load_lds16(gb1 + k0, lb + 2048);
    };

    f32x4 acc[4][4] = {};
    const int nIt = K >> 5;

    // prologue: stage tiles 0 and 1; wait for tile 0 only (tile 1 in flight)
    stg(0);
    if (nIt > 1) {
        stg(1);
        asm volatile("s_waitcnt vmcnt(4)" ::: "memory");
    } else {
        asm volatile("s_waitcnt vmcnt(0)" ::: "memory");
    }
    __builtin_amdgcn_s_barrier();
    __builtin_amdgcn_sched_barrier(0);

    int cur = 0;
#pragma unroll 1
    for (int it = 0; it < nIt; ++it) {
        const bool pre = (it + 2 < nIt);
        if (pre) stg(it + 2);
        bf16x8 af[4], bfr[4];
#pragma unroll
        for (int i = 0; i < 4; ++i) af[i]  = *(const bf16x8*)(&As[cur][wm + i * 16 + lrow][lko]);
#pragma unroll
        for (int j = 0; j < 4; ++j) bfr[j] = *(const bf16x8*)(&Bs[cur][wn + j * 16 + lrow][lko]);
#pragma unroll
        for (int i = 0; i < 4; ++i)
#pragma unroll
            for (int j = 0; j < 4; ++j)
                acc[i][j] = __builtin_amdgcn_mfma_f32_16x16x32_bf16(af[i], bfr[j], acc[i][j], 0, 0, 0);
        // allow the 4 loads of stage(it+2) to stay in flight across the
        // barrier; everything older (stage it+1) must be complete.
        if (pre) asm volatile("s_waitcnt vmcnt(4)" ::: "memory");
        else     asm volatile("s_waitcnt vmcnt(0)" ::: "memory");
        __builtin_amdgcn_s_barrier();
        __builtin_amdgcn_sched_barrier(0);
        cur = (cur == 2) ? 0 : cur + 1;
    }
#pragma unroll
    for (int i = 0; i < 4; ++i) {
        int mrow0 = m0 + wm + i * 16 + quad * 4;
#pragma unroll
        for (int j = 0; j < 4; ++j) {
            int ncol = n0 + wn + j * 16 + lrow;
#pragma unroll
            for (int r = 0; r < 4; ++r)
                C[(long)(mrow0 + r) * N + ncol] = (CT)acc[i][j][r];
        }
    }
}

// ---------------------------------------------------------------------------
// Per-head RMSNorm, wave per 128-vector, in-place.
__global__ __launch_bounds__(256) void rmsnorm_head(bf16* __restrict__ X,
                                                    const float* __restrict__ W,
                                                    int nvec, int lhpr, int stride) {
    int v = blockIdx.x * 4 + (threadIdx.x >> 6);
    int lane = threadIdx.x & 63;
    if (v >= nvec) return;
    int row = v >> lhpr, head = v & ((1 << lhpr) - 1);
    bf16* x = X + (long)row * stride + head * HD;
    float fa = (float)x[lane * 2], fb = (float)x[lane * 2 + 1];
    float ss = fa * fa + fb * fb;
#pragma unroll
    for (int off = 1; off < 64; off <<= 1) ss += __shfl_xor(ss, off, 64);
    float r = rsqrtf(ss * (1.0f / 128.0f) + 1e-5f);
    x[lane * 2]     = (bf16)(fa * r * W[lane * 2]);
    x[lane * 2 + 1] = (bf16)(fb * r * W[lane * 2 + 1]);
}

// ---------------------------------------------------------------------------
// Repack K (post-RMSNorm) into fragment-major tiles:
// kf[(b*4+kvh)*32 + kt][nt(4)][ks(4)][lane(64)][8] with
//   key = kt*64 + nt*16 + (lane&15), d = ks*32 + (lane>>4)*8 + j.
__global__ __launch_bounds__(256) void repack_k(const bf16* __restrict__ xkv,
                                                bf16* __restrict__ kf) {
    int kt = blockIdx.x, kvh = blockIdx.y, b = blockIdx.z;
    int tid = threadIdx.x, lane = tid & 63, ks = tid >> 6;
    int lrow = lane & 15, quad = lane >> 4;
    const bf16* src = xkv + ((long)b * SEQ + kt * 64) * 1024 + kvh * HD;
    bf16* dst = kf + ((long)((b * NKVH + kvh) * 32 + kt)) * 8192;
#pragma unroll
    for (int nt = 0; nt < 4; ++nt) {
        bf16x8 v = *(const bf16x8*)(src + (long)(nt * 16 + lrow) * 1024 + ks * 32 + quad * 8);
        *(bf16x8*)(dst + ((nt * 4 + ks) * 64 + lane) * 8) = v;
    }
}

// Repack V^T into fragment-major tiles:
// vf[(b*4+kvh)*32 + kt][nt(4)][dt(8)][lane(64)][4] with
//   d = dt*16 + (lane&15), key = kt*64 + nt*16 + (lane>>4)*4 + j.
__global__ __launch_bounds__(256) void repack_v(const bf16* __restrict__ xkv,
                                                bf16* __restrict__ vf) {
    __shared__ bf16 Vls[64][136];
    int kt = blockIdx.x, kvh = blockIdx.y, b = blockIdx.z;
    int tid = threadIdx.x;
    const bf16* src = xkv + ((long)b * SEQ + kt * 64) * 1024 + 512 + kvh * HD;
#pragma unroll
    for (int p = 0; p < 4; ++p) {
        int c = p * 256 + tid;
        int r = c >> 4, dc = (c & 15) * 8;
        *(uint4*)(&Vls[r][dc]) = *(const uint4*)(src + (long)r * 1024 + dc);
    }
    __syncthreads();
    int lane = tid & 63, w = tid >> 6, lrow = lane & 15, quad = lane >> 4;
    bf16* dst = vf + ((long)((b * NKVH + kvh) * 32 + kt)) * 8192;
#pragma unroll
    for (int nt = 0; nt < 4; ++nt)
#pragma unroll
        for (int dtl = 0; dtl < 2; ++dtl) {
            int dt = w * 2 + dtl;
            bf16x4 v = {Vls[nt * 16 + quad * 4 + 0][dt * 16 + lrow],
                        Vls[nt * 16 + quad * 4 + 1][dt * 16 + lrow],
                        Vls[nt * 16 + quad * 4 + 2][dt * 16 + lrow],
                        Vls[nt * 16 + quad * 4 + 3][dt * 16 + lrow]};
            *(bf16x4*)(dst + ((nt * 8 + dt) * 64 + lane) * 4) = v;
        }
}

// ---------------------------------------------------------------------------
// Flash attention: R6 structure FROZEN (best measured: 69.9 us, VGPR 52).
// 512-thread blocks, 8 waves = 4 q-subtiles (w4) x 2 key-parity groups
// (grpW); 2-way split-K merge at tile end via LDS scratch. Grid 512 ->
// 2 blocks/CU -> 16 waves/CU. XCD pinning: (b,kvh)=bid&7. Paired q-tiles
// {31-p,p}: 33 identical iterations per block under any placement.
__global__ __launch_bounds__(512, 4) void attn_kernel(const bf16* __restrict__ Q,
                                                      const bf16* __restrict__ KF,
                                                      const bf16* __restrict__ VF,
                                                      bf16* __restrict__ O) {
    __shared__ bf16 Kf[2][8192];   // [buf][half(2)·nt(2)·ks(4)·512] — 32 KB
    __shared__ bf16 Vf[2][8192];   // [buf][half(2)·nt(2)·dt(8)·256] — 32 KB
    const int tid = threadIdx.x, wave = tid >> 6, lane = tid & 63;
    const int w4 = wave & 3, grpW = wave >> 2;
    const int bid = blockIdx.x;
    const int grp = bid & 7;                  // -> XCD via bid%8 round-robin
    const int b = grp >> 2, kvh = grp & 3;
    const int slot = bid >> 3;                // 0..63
    const int pr = slot & 15;
    const int h = kvh * 4 + (slot >> 4);
    const int lrow = lane & 15, quad = lane >> 4;
    const float scl2 = 0.12751744f;     // (1/sqrt(128)) * log2(e)
    const float THR = 62.7f;            // ~8 ln-units in raw-score domain

    const int qt1 = 31 - pr, qt2 = pr;

    const bf16* kfb = KF + ((long)(b * NKVH + kvh) * 32) * 8192;
    const bf16* vfb = VF + ((long)(b * NKVH + kvh) * 32) * 8192;

    // stage 64-key pair (== repack tile) into buffer bsel: 512thr x 2x16B each
    auto stage = [&](int pair, int bsel) {
        const bf16* kg = kfb + (long)pair * 8192 + tid * 8;
        const bf16* vg = vfb + (long)pair * 8192 + tid * 8;
        bf16* kd = &Kf[bsel][0] + tid * 8;
        bf16* vd = &Vf[bsel][0] + tid * 8;
        load_lds16(kg, kd);
        load_lds16(kg + 4096, kd + 4096);
        load_lds16(vg, vd);
        load_lds16(vg + 4096, vd + 4096);
    };

    float m_i = NEG, l_i = 0.f;
    f32x4 oT[8] = {};   // out^T: d = dt*16 + quad*4 + r, q = lane&15
    bf16x8 bqw[4];

    // split-K combine (group1 -> group0 via Vf scratch) + output write + reset
    auto combine_write_reset = [&](int qrow) {
        float a1keep = 0.f;
        float* vs = (float*)&Vf[0][0];
        const int sl = w4 * 64 + lane;
        __syncthreads();
        if (grpW == 1) {
            float* d = vs + sl * 18;
#pragma unroll
            for (int dt = 0; dt < 4; ++dt)
#pragma unroll
                for (int r = 0; r < 4; ++r) d[dt * 4 + r] = oT[dt][r];
            d[16] = m_i; d[17] = l_i;
        }
        __syncthreads();
        if (grpW == 0) {
            const float* s = vs + sl * 18;
            float m1 = s[16], l1 = s[17];
            float ms = fmaxf(m_i, m1);
            float a0 = fast_exp2((m_i - ms) * scl2);
            float a1 = fast_exp2((m1 - ms) * scl2);
            a1keep = a1;
            l_i = a0 * l_i + a1 * l1;
#pragma unroll
            for (int dt = 0; dt < 4; ++dt)
#pragma unroll
                for (int r = 0; r < 4; ++r)
                    oT[dt][r] = a0 * oT[dt][r] + a1 * s[dt * 4 + r];
#pragma unroll
            for (int dt = 4; dt < 8; ++dt)
#pragma unroll
                for (int r = 0; r < 4; ++r) oT[dt][r] *= a0;
            m_i = ms;
        }
        __syncthreads();
        if (grpW == 1) {
            float* d = vs + sl * 16;
#pragma unroll
            for (int dt = 4; dt < 8; ++dt)
#pragma unroll
                for (int r = 0; r < 4; ++r) d[(dt - 4) * 4 + r] = oT[dt][r];
        }
        __syncthreads();
        if (grpW == 0) {
            const float* s = vs + sl * 16;
#pragma unroll
            for (int dt = 4; dt < 8; ++dt)
#pragma unroll
                for (int r = 0; r < 4; ++r) oT[dt][r] += a1keep * s[(dt - 4) * 4 + r];
            float inv_l = 1.0f / l_i;
            bf16* obase = O + ((long)(b * SEQ + qrow)) * (NH * HD) + h * HD;
#pragma unroll
            for (int dt = 0; dt < 8; ++dt) {
                bf16x4 o = {(bf16)(oT[dt][0] * inv_l), (bf16)(oT[dt][1] * inv_l),
                            (bf16)(oT[dt][2] * inv_l), (bf16)(oT[dt][3] * inv_l)};
                *(bf16x4*)(obase + dt * 16 + quad * 4) = o;
            }
        }
        __syncthreads();   // scratch/LDS free for restage
        m_i = NEG; l_i = 0.f;
#pragma unroll
        for (int dt = 0; dt < 8; ++dt)
#pragma unroll
            for (int r = 0; r < 4; ++r) oT[dt][r] = 0.f;
    };

    // process the current staged pair: group's 32-key block kbg
    auto process = [&](int i, int itN, int myq, int cur) {
        const int kbg = 2 * i + grpW;
        const bool diag = (i == itN - 1);
        const bf16* kbase = &Kf[cur][0] + grpW * 4096;
        const bf16* vbase = &Vf[cur][0] + grpW * 4096;

        f32x4 st[2];
        __builtin_amdgcn_s_setprio(1);
#pragma unroll
        for (int nt = 0; nt < 2; ++nt) {
            f32x4 acc = {};
#pragma unroll
            for (int ks = 0; ks < 4; ++ks) {
                bf16x8 ak = *(const bf16x8*)(kbase + (nt * 4 + ks) * 512 + lane * 8);
                acc = __builtin_amdgcn_mfma_f32_16x16x32_bf16(ak, bqw[ks], acc, 0, 0, 0);
            }
            st[nt] = acc;
        }
        __builtin_amdgcn_s_setprio(0);
        if (diag) {
#pragma unroll
            for (int nt = 0; nt < 2; ++nt) {
                int kp0 = kbg * 32 + nt * 16 + quad * 4;
#pragma unroll
                for (int r = 0; r < 4; ++r)
                    if (kp0 + r > myq) st[nt][r] = NEG;
            }
        }

        float mx = st[0][0];
#pragma unroll
        for (int nt = 0; nt < 2; ++nt)
#pragma unroll
            for (int r = 0; r < 4; ++r) mx = fmaxf(mx, st[nt][r]);
        mx = fmaxf(mx, __shfl_xor(mx, 16, 64));
        mx = fmaxf(mx, __shfl_xor(mx, 32, 64));

        if (!__all(mx - m_i <= THR)) {
            float mnew = fmaxf(m_i, mx);
            float alpha = fast_exp2((m_i - mnew) * scl2);
            l_i *= alpha;
#pragma unroll
            for (int dt = 0; dt < 8; ++dt)
#pragma unroll
                for (int r = 0; r < 4; ++r) oT[dt][r] *= alpha;
            m_i = mnew;
        }
        float rs = 0.f;
#pragma unroll
        for (int nt = 0; nt < 2; ++nt)
#pragma unroll
            for (int r = 0; r < 4; ++r) {
                float p = fast_exp2((st[nt][r] - m_i) * scl2);
                st[nt][r] = p;
                rs += p;
            }
        rs += __shfl_xor(rs, 16, 64);
        rs += __shfl_xor(rs, 32, 64);
        l_i += rs;

        bf16x4 pf[2];
#pragma unroll
        for (int nt = 0; nt < 2; ++nt) {
            bf16x4 tt = {(bf16)st[nt][0], (bf16)st[nt][1],
                         (bf16)st[nt][2], (bf16)st[nt][3]};
            pf[nt] = tt;
        }

        __builtin_amdgcn_s_setprio(1);
#pragma unroll
        for (int nt = 0; nt < 2; ++nt)
#pragma unroll
            for (int dt = 0; dt < 8; ++dt) {
                bf16x4 av = *(const bf16x4*)(vbase + (nt * 8 + dt) * 256 + lane * 4);
                oT[dt] = mfma_16x16x16(av, pf[nt], oT[dt]);
            }
        __builtin_amdgcn_s_setprio(0);
    };

    // ---- tile 1: qt1, it1 = qt1+1 staged pairs --------------------------
    const int it1 = qt1 + 1;
    const int myq1 = qt1 * 64 + w4 * 16 + lrow;
    {
        const bf16* qrow = Q + ((long)(b * SEQ + myq1)) * (NH * HD) + h * HD;
#pragma unroll
        for (int ks = 0; ks < 4; ++ks)
            bqw[ks] = *(const bf16x8*)(qrow + ks * 32 + quad * 8);
    }
    stage(0, 0);
    __syncthreads();
#pragma unroll 1
    for (int i = 0; i < it1; ++i) {
        const int cur = i & 1;
        if (i + 1 < it1) stage(i + 1, cur ^ 1);
        process(i, it1, myq1, cur);
        __syncthreads();
    }
    combine_write_reset(myq1);

    // ---- tile 2: qt2, it2 = qt2+1 staged pairs --------------------------
    const int it2 = qt2 + 1;
    const int myq2 = qt2 * 64 + w4 * 16 + lrow;
    {
        const bf16* qrow = Q + ((long)(b * SEQ + myq2)) * (NH * HD) + h * HD;
#pragma unroll
        for (int ks = 0; ks < 4; ++ks)
            bqw[ks] = *(const bf16x8*)(qrow + ks * 32 + quad * 8);
    }
    stage(0, 0);
    __syncthreads();
#pragma unroll 1
    for (int i = 0; i < it2; ++i) {
        const int cur = i & 1;
        if (i + 1 < it2) stage(i + 1, cur ^ 1);
        process(i, it2, myq2, cur);
        __syncthreads();
    }
    combine_write_reset(myq2);
}

// ---------------------------------------------------------------------------
extern "C" void kernel_launch(void* const* d_in, const int* in_sizes, int n_in,
                              void* d_out, int out_size, void* d_ws, size_t ws_size,
                              hipStream_t stream) {
    const float* q_stream  = (const float*)d_in[0];
    const float* kv_stream = (const float*)d_in[1];
    const float* wq  = (const float*)d_in[2];
    const float* wk  = (const float*)d_in[3];
    const float* wv  = (const float*)d_in[4];
    const float* wo  = (const float*)d_in[5];
    const float* qnw = (const float*)d_in[6];
    const float* knw = (const float*)d_in[7];
    float* out = (float*)d_out;

    // workspace (bf16 elems), total 30M elems = 60MB
    bf16* ws   = (bf16*)d_ws;
    bf16* sb   = ws;                        // 8M: stream buf, later attn out
    bf16* wqT  = ws + 8L * 1024 * 1024;     // 4M: wq^T, later wo^T
    bf16* wkvT = wqT + 4L * 1024 * 1024;    // 2M: [wk^T ; wv^T] = [1024][2048]
    bf16* xq   = wkvT + 2L * 1024 * 1024;   // 8M: [4096][2048]
    bf16* xkv  = xq + 8L * 1024 * 1024;     // 4M: [4096][1024] = [K | V]
    bf16* kf   = xkv + 4L * 1024 * 1024;    // 2M: K fragment-major
    bf16* vf   = kf + 2L * 1024 * 1024;     // 2M: V^T fragment-major

    dim3 tb(32, 8);
    cvt_f32_bf16<<<4096, 256, 0, stream>>>(q_stream, sb, 1048576);
    transpose2d<<<dim3(64, 64), tb, 0, stream>>>(wq, wqT, 2048, 2048);
    transpose2d<<<dim3(16, 64), tb, 0, stream>>>(wk, wkvT, 2048, 512);
    transpose2d<<<dim3(16, 64), tb, 0, stream>>>(wv, wkvT + 512L * 2048, 2048, 512);
    gemm_bt<bf16><<<dim3(16, 32), 256, 0, stream>>>(sb, wqT, xq, 4096, 2048, 2048);
    cvt_f32_bf16<<<4096, 256, 0, stream>>>(kv_stream, sb, 1048576);
    transpose2d<<<dim3(64, 64), tb, 0, stream>>>(wo, wqT, 2048, 2048);
    gemm_bt<bf16><<<dim3(8, 32), 256, 0, stream>>>(sb, wkvT, xkv, 4096, 1024, 2048);
    rmsnorm_head<<<(4096 * 16) / 4, 256, 0, stream>>>(xq, qnw, 4096 * 16, 4, 2048);
    rmsnorm_head<<<(4096 * 4) / 4, 256, 0, stream>>>(xkv, knw, 4096 * 4, 2, 1024);
    repack_k<<<dim3(32, 4, 2), 256, 0, stream>>>(xkv, kf);
    repack_v<<<dim3(32, 4, 2), 256, 0, stream>>>(xkv, vf);
    attn_kernel<<<dim3(512), dim3(512), 0, stream>>>(xq, kf, vf, sb);
    gemm_bt<float><<<dim3(16, 32), 256, 0, stream>>>(sb, wqT, out, 4096, 2048, 2048);

    (void)in_sizes; (void)n_in; (void)out_size; (void)ws_size;
}

// Round 11
// 377.499 us; speedup vs baseline: 1.0315x; 1.0315x over previous
//
#include <hip/hip_runtime.h>
#include <cstdint>

// ---------------------------------------------------------------------------
// JanusCrossAttention: B=2,S=2048, Q_DIM=KV_DIM=2048, H=16, D=128, KVH=4
// I/O fp32; internals bf16 MFMA, fp32 accumulate.
// R11: launch-count reduction 14 -> 9 (accounting audit: 65-140 us of the
// 389 us total is inter-dispatch overhead across 13 gaps; kernels themselves
// sum to ~250-325). Fusions: cvt_q+cvt_kv (kv-bf16 staged in d_out scratch,
// overwritten by the final GEMM), wq+wk+wv transposes, both rmsnorms, both
// repacks. GEMM reverted to R9's measured-best double-buffer (R10's counted
// vmcnt tri-buffer was neutral-negative -> staging latency is NOT the GEMM
// binder; next lever there is the 256^2 8-phase structure port).
// Attn: R6 structure FROZEN (69.9 us, VGPR 52).
// ---------------------------------------------------------------------------

using bf16 = __bf16;
using bf16x4 = __attribute__((ext_vector_type(4))) __bf16;
using bf16x8 = __attribute__((ext_vector_type(8))) __bf16;
using s16x4  = __attribute__((ext_vector_type(4))) short;
using f32x4  = __attribute__((ext_vector_type(4))) float;

#define SEQ 2048
#define NH 16
#define NKVH 4
#define HD 128

// finite "minus infinity": avoids inf-inf NaNs in the split-K defer-max path
#define NEG (-3.0e38f)

// 16x16x16 bf16 MFMA (K=16) — C layout of a prior 16x16 MFMA feeds B directly.
#if defined(__has_builtin)
#if __has_builtin(__builtin_amdgcn_mfma_f32_16x16x16bf16_1k)
#define HAVE_1K 1
#endif
#endif
__device__ __forceinline__ f32x4 mfma_16x16x16(bf16x4 a, bf16x4 b, f32x4 c) {
#ifdef HAVE_1K
    return __builtin_amdgcn_mfma_f32_16x16x16bf16_1k(
        __builtin_bit_cast(s16x4, a), __builtin_bit_cast(s16x4, b), c, 0, 0, 0);
#else
    f32x4 d;
    asm volatile("v_mfma_f32_16x16x16_bf16 %0, %1, %2, %3"
                 : "=v"(d) : "v"(a), "v"(b), "v"(c));
    return d;
#endif
}

// native exp2 (v_exp_f32)
__device__ __forceinline__ float fast_exp2(float x) {
#if defined(__has_builtin)
#if __has_builtin(__builtin_amdgcn_exp2f)
    return __builtin_amdgcn_exp2f(x);
#else
    return exp2f(x);
#endif
#else
    return exp2f(x);
#endif
}

// async global->LDS, 16B per lane. LDS dest must be wave-uniform base + lane*16.
__device__ __forceinline__ void load_lds16(const bf16* g, bf16* l) {
    __builtin_amdgcn_global_load_lds(
        (const __attribute__((address_space(1))) unsigned int*)g,
        (__attribute__((address_space(3))) unsigned int*)l, 16, 0, 0);
}

// ---------------------------------------------------------------------------
// fused cvt: q_stream -> oq (bf16), kv_stream -> okv (bf16). 2 x 1048576
// 8-elem units, one launch.
__global__ __launch_bounds__(256) void cvt_both(const float* __restrict__ q,
                                                const float* __restrict__ kv,
                                                bf16* __restrict__ oq,
                                                bf16* __restrict__ okv) {
    int i = blockIdx.x * 256 + threadIdx.x;
    const float* in;
    bf16* out;
    int j;
    if (i < 1048576) { in = q;  out = oq;  j = i; }
    else             { in = kv; out = okv; j = i - 1048576; }
    const float4* p = (const float4*)in + (long)j * 2;
    float4 f0 = p[0], f1 = p[1];
    bf16x8 o = {(bf16)f0.x, (bf16)f0.y, (bf16)f0.z, (bf16)f0.w,
                (bf16)f1.x, (bf16)f1.y, (bf16)f1.z, (bf16)f1.w};
    *((bf16x8*)out + j) = o;
}

// 2D transpose + cast core: in fp32 [R][C] -> out bf16 [C][R]
__device__ __forceinline__ void transpose_body(const float* in, bf16* out,
                                               int R, int C, int bx, int by) {
    __shared__ bf16 tile[32][33];
    int x  = bx * 32 + threadIdx.x;
    int y0 = by * 32 + threadIdx.y;
#pragma unroll
    for (int i = 0; i < 32; i += 8) {
        int y = y0 + i;
        if (y < R && x < C) tile[threadIdx.y + i][threadIdx.x] = (bf16)in[(long)y * C + x];
    }
    __syncthreads();
    int ox  = by * 32 + threadIdx.x;
    int oy0 = bx * 32 + threadIdx.y;
#pragma unroll
    for (int i = 0; i < 32; i += 8) {
        int oy = oy0 + i;
        if (oy < C && ox < R) out[(long)oy * R + ox] = tile[threadIdx.x][threadIdx.y + i];
    }
}

// single-matrix transpose (used for wo after gemm1 releases wqT)
__global__ void transpose2d(const float* __restrict__ in, bf16* __restrict__ out,
                            int R, int C) {
    transpose_body(in, out, R, C, blockIdx.x, blockIdx.y);
}

// fused transpose: z=0 -> wq (2048x2048); z=1,x<16 -> wk, 16<=x<32 -> wv
// (each 2048x512, packed into wkvT = [wk^T ; wv^T]).
__global__ void transpose_merged(const float* __restrict__ wq,
                                 const float* __restrict__ wk,
                                 const float* __restrict__ wv,
                                 bf16* __restrict__ wqT,
                                 bf16* __restrict__ wkvT) {
    if (blockIdx.z == 0) {
        transpose_body(wq, wqT, 2048, 2048, blockIdx.x, blockIdx.y);
    } else {
        int x = blockIdx.x;
        if (x >= 32) return;
        if (x < 16) transpose_body(wk, wkvT, 2048, 512, x, blockIdx.y);
        else        transpose_body(wv, wkvT + 512L * 2048, 2048, 512, x - 16, blockIdx.y);
    }
}

// ---------------------------------------------------------------------------
// GEMM: C[M][N] = A[M][K] @ BT[N][K]^T, bf16 in, fp32 acc, CT out.
// 128x128 tile, BK=32, global_load_lds width-16 staging, double-buffered
// (R9 config — measured best). XCD swizzle (bid%8 -> XCD, R3-proven); all
// call-site grids are %8==0.
template <typename CT>
__global__ __launch_bounds__(256) void gemm_bt(const bf16* __restrict__ A,
                                               const bf16* __restrict__ BT,
                                               CT* __restrict__ C,
                                               int M, int N, int K) {
    __shared__ bf16 As[2][128][32];
    __shared__ bf16 Bs[2][128][32];
    const int tid  = threadIdx.x;
    const int wave = tid >> 6, lane = tid & 63;
    const int nwg = gridDim.x * gridDim.y;
    const int bid = blockIdx.y * gridDim.x + blockIdx.x;
    const int swz = (bid & 7) * (nwg >> 3) + (bid >> 3);
    const int bx = swz % gridDim.x, by = swz / gridDim.x;
    const int m0 = by * 128, n0 = bx * 128;
    const int wm = (wave >> 1) * 64, wn = (wave & 1) * 64;
    const int lrow = lane & 15, quad = lane >> 4;
    const int lko = quad * 8;

    const bf16* ga0 = A  + (long)(m0 + (tid >> 2)) * K + (tid & 3) * 8;
    const bf16* ga1 = ga0 + 64L * K;
    const bf16* gb0 = BT + (long)(n0 + (tid >> 2)) * K + (tid & 3) * 8;
    const bf16* gb1 = gb0 + 64L * K;
    bf16* la0 = &As[0][0][0] + tid * 8;
    bf16* lb0 = &Bs[0][0][0] + tid * 8;

    f32x4 acc[4][4] = {};

    const int nIt = K >> 5;
    // prologue: stage k-tile 0 into buffer 0
    load_lds16(ga0, la0);
    load_lds16(ga1, la0 + 2048);
    load_lds16(gb0, lb0);
    load_lds16(gb1, lb0 + 2048);
    __syncthreads();

#pragma unroll 1
    for (int it = 0; it < nIt; ++it) {
        const int cur = it & 1;
        if (it + 1 < nIt) {
            const int k0 = (it + 1) * 32;
            bf16* la = la0 + (cur ^ 1) * 4096;
            bf16* lb = lb0 + (cur ^ 1) * 4096;
            load_lds16(ga0 + k0, la);
            load_lds16(ga1 + k0, la + 2048);
            load_lds16(gb0 + k0, lb);
            load_lds16(gb1 + k0, lb + 2048);
        }
        bf16x8 af[4], bfr[4];
#pragma unroll
        for (int i = 0; i < 4; ++i) af[i]  = *(const bf16x8*)(&As[cur][wm + i * 16 + lrow][lko]);
#pragma unroll
        for (int j = 0; j < 4; ++j) bfr[j] = *(const bf16x8*)(&Bs[cur][wn + j * 16 + lrow][lko]);
#pragma unroll
        for (int i = 0; i < 4; ++i)
#pragma unroll
            for (int j = 0; j < 4; ++j)
                acc[i][j] = __builtin_amdgcn_mfma_f32_16x16x32_bf16(af[i], bfr[j], acc[i][j], 0, 0, 0);
        __syncthreads();   // releases buffer cur for restage at it+1; drains staged loads
    }
#pragma unroll
    for (int i = 0; i < 4; ++i) {
        int mrow0 = m0 + wm + i * 16 + quad * 4;
#pragma unroll
        for (int j = 0; j < 4; ++j) {
            int ncol = n0 + wn + j * 16 + lrow;
#pragma unroll
            for (int r = 0; r < 4; ++r)
                C[(long)(mrow0 + r) * N + ncol] = (CT)acc[i][j][r];
        }
    }
}

// ---------------------------------------------------------------------------
// Fused per-head RMSNorm for xq (65536 vecs, 16 heads, stride 2048, qnw) and
// xkv K-half (16384 vecs, 4 heads, stride 1024, knw). Wave per 128-vector,
// in-place; branch is wave-uniform (one vector per wave).
__global__ __launch_bounds__(256) void rmsnorm_merged(bf16* __restrict__ XQ,
                                                      bf16* __restrict__ XKV,
                                                      const float* __restrict__ QW,
                                                      const float* __restrict__ KW) {
    int v = blockIdx.x * 4 + (threadIdx.x >> 6);
    int lane = threadIdx.x & 63;
    bf16* X; const float* W; int lhpr, stride, vv;
    if (v < 65536) { X = XQ;  W = QW; lhpr = 4; stride = 2048; vv = v; }
    else           { X = XKV; W = KW; lhpr = 2; stride = 1024; vv = v - 65536; }
    int row = vv >> lhpr, head = vv & ((1 << lhpr) - 1);
    bf16* x = X + (long)row * stride + head * HD;
    float fa = (float)x[lane * 2], fb = (float)x[lane * 2 + 1];
    float ss = fa * fa + fb * fb;
#pragma unroll
    for (int off = 1; off < 64; off <<= 1) ss += __shfl_xor(ss, off, 64);
    float r = rsqrtf(ss * (1.0f / 128.0f) + 1e-5f);
    x[lane * 2]     = (bf16)(fa * r * W[lane * 2]);
    x[lane * 2 + 1] = (bf16)(fb * r * W[lane * 2 + 1]);
}

// ---------------------------------------------------------------------------
// Fused repack of K and V^T into MFMA-fragment-major tiles (one launch).
// kf[(b*4+kvh)*32 + kt][nt(4)][ks(4)][lane(64)][8]:
//   key = kt*64 + nt*16 + (lane&15), d = ks*32 + (lane>>4)*8 + j.
// vf[(b*4+kvh)*32 + kt][nt(4)][dt(8)][lane(64)][4]:
//   d = dt*16 + (lane&15), key = kt*64 + nt*16 + (lane>>4)*4 + j.
__global__ __launch_bounds__(256) void repack_merged(const bf16* __restrict__ xkv,
                                                     bf16* __restrict__ kf,
                                                     bf16* __restrict__ vf) {
    __shared__ bf16 Vls[64][136];
    int kt = blockIdx.x, kvh = blockIdx.y, b = blockIdx.z;
    int tid = threadIdx.x, lane = tid & 63;
    int lrow = lane & 15, quad = lane >> 4;

    // ---- K part (no LDS) ----
    {
        int ks = tid >> 6;
        const bf16* src = xkv + ((long)b * SEQ + kt * 64) * 1024 + kvh * HD;
        bf16* dst = kf + ((long)((b * NKVH + kvh) * 32 + kt)) * 8192;
#pragma unroll
        for (int nt = 0; nt < 4; ++nt) {
            bf16x8 v = *(const bf16x8*)(src + (long)(nt * 16 + lrow) * 1024 + ks * 32 + quad * 8);
            *(bf16x8*)(dst + ((nt * 4 + ks) * 64 + lane) * 8) = v;
        }
    }

    // ---- V part (transpose via LDS) ----
    {
        const bf16* src = xkv + ((long)b * SEQ + kt * 64) * 1024 + 512 + kvh * HD;
#pragma unroll
        for (int p = 0; p < 4; ++p) {
            int c = p * 256 + tid;
            int r = c >> 4, dc = (c & 15) * 8;
            *(uint4*)(&Vls[r][dc]) = *(const uint4*)(src + (long)r * 1024 + dc);
        }
        __syncthreads();
        int w = tid >> 6;
        bf16* dst = vf + ((long)((b * NKVH + kvh) * 32 + kt)) * 8192;
#pragma unroll
        for (int nt = 0; nt < 4; ++nt)
#pragma unroll
            for (int dtl = 0; dtl < 2; ++dtl) {
                int dt = w * 2 + dtl;
                bf16x4 v = {Vls[nt * 16 + quad * 4 + 0][dt * 16 + lrow],
                            Vls[nt * 16 + quad * 4 + 1][dt * 16 + lrow],
                            Vls[nt * 16 + quad * 4 + 2][dt * 16 + lrow],
                            Vls[nt * 16 + quad * 4 + 3][dt * 16 + lrow]};
                *(bf16x4*)(dst + ((nt * 8 + dt) * 64 + lane) * 4) = v;
            }
    }
}

// ---------------------------------------------------------------------------
// Flash attention: R6 structure FROZEN (best measured: 69.9 us, VGPR 52).
// 512-thread blocks, 8 waves = 4 q-subtiles (w4) x 2 key-parity groups
// (grpW); 2-way split-K merge at tile end via LDS scratch. Grid 512 ->
// 2 blocks/CU -> 16 waves/CU. XCD pinning: (b,kvh)=bid&7. Paired q-tiles
// {31-p,p}: 33 identical iterations per block under any placement.
__global__ __launch_bounds__(512, 4) void attn_kernel(const bf16* __restrict__ Q,
                                                      const bf16* __restrict__ KF,
                                                      const bf16* __restrict__ VF,
                                                      bf16* __restrict__ O) {
    __shared__ bf16 Kf[2][8192];   // [buf][half(2)·nt(2)·ks(4)·512] — 32 KB
    __shared__ bf16 Vf[2][8192];   // [buf][half(2)·nt(2)·dt(8)·256] — 32 KB
    const int tid = threadIdx.x, wave = tid >> 6, lane = tid & 63;
    const int w4 = wave & 3, grpW = wave >> 2;
    const int bid = blockIdx.x;
    const int grp = bid & 7;                  // -> XCD via bid%8 round-robin
    const int b = grp >> 2, kvh = grp & 3;
    const int slot = bid >> 3;                // 0..63
    const int pr = slot & 15;
    const int h = kvh * 4 + (slot >> 4);
    const int lrow = lane & 15, quad = lane >> 4;
    const float scl2 = 0.12751744f;     // (1/sqrt(128)) * log2(e)
    const float THR = 62.7f;            // ~8 ln-units in raw-score domain

    const int qt1 = 31 - pr, qt2 = pr;

    const bf16* kfb = KF + ((long)(b * NKVH + kvh) * 32) * 8192;
    const bf16* vfb = VF + ((long)(b * NKVH + kvh) * 32) * 8192;

    // stage 64-key pair (== repack tile) into buffer bsel: 512thr x 2x16B each
    auto stage = [&](int pair, int bsel) {
        const bf16* kg = kfb + (long)pair * 8192 + tid * 8;
        const bf16* vg = vfb + (long)pair * 8192 + tid * 8;
        bf16* kd = &Kf[bsel][0] + tid * 8;
        bf16* vd = &Vf[bsel][0] + tid * 8;
        load_lds16(kg, kd);
        load_lds16(kg + 4096, kd + 4096);
        load_lds16(vg, vd);
        load_lds16(vg + 4096, vd + 4096);
    };

    float m_i = NEG, l_i = 0.f;
    f32x4 oT[8] = {};   // out^T: d = dt*16 + quad*4 + r, q = lane&15
    bf16x8 bqw[4];

    // split-K combine (group1 -> group0 via Vf scratch) + output write + reset
    auto combine_write_reset = [&](int qrow) {
        float a1keep = 0.f;
        float* vs = (float*)&Vf[0][0];
        const int sl = w4 * 64 + lane;
        __syncthreads();
        if (grpW == 1) {
            float* d = vs + sl * 18;
#pragma unroll
            for (int dt = 0; dt < 4; ++dt)
#pragma unroll
                for (int r = 0; r < 4; ++r) d[dt * 4 + r] = oT[dt][r];
            d[16] = m_i; d[17] = l_i;
        }
        __syncthreads();
        if (grpW == 0) {
            const float* s = vs + sl * 18;
            float m1 = s[16], l1 = s[17];
            float ms = fmaxf(m_i, m1);
            float a0 = fast_exp2((m_i - ms) * scl2);
            float a1 = fast_exp2((m1 - ms) * scl2);
            a1keep = a1;
            l_i = a0 * l_i + a1 * l1;
#pragma unroll
            for (int dt = 0; dt < 4; ++dt)
#pragma unroll
                for (int r = 0; r < 4; ++r)
                    oT[dt][r] = a0 * oT[dt][r] + a1 * s[dt * 4 + r];
#pragma unroll
            for (int dt = 4; dt < 8; ++dt)
#pragma unroll
                for (int r = 0; r < 4; ++r) oT[dt][r] *= a0;
            m_i = ms;
        }
        __syncthreads();
        if (grpW == 1) {
            float* d = vs + sl * 16;
#pragma unroll
            for (int dt = 4; dt < 8; ++dt)
#pragma unroll
                for (int r = 0; r < 4; ++r) d[(dt - 4) * 4 + r] = oT[dt][r];
        }
        __syncthreads();
        if (grpW == 0) {
            const float* s = vs + sl * 16;
#pragma unroll
            for (int dt = 4; dt < 8; ++dt)
#pragma unroll
                for (int r = 0; r < 4; ++r) oT[dt][r] += a1keep * s[(dt - 4) * 4 + r];
            float inv_l = 1.0f / l_i;
            bf16* obase = O + ((long)(b * SEQ + qrow)) * (NH * HD) + h * HD;
#pragma unroll
            for (int dt = 0; dt < 8; ++dt) {
                bf16x4 o = {(bf16)(oT[dt][0] * inv_l), (bf16)(oT[dt][1] * inv_l),
                            (bf16)(oT[dt][2] * inv_l), (bf16)(oT[dt][3] * inv_l)};
                *(bf16x4*)(obase + dt * 16 + quad * 4) = o;
            }
        }
        __syncthreads();   // scratch/LDS free for restage
        m_i = NEG; l_i = 0.f;
#pragma unroll
        for (int dt = 0; dt < 8; ++dt)
#pragma unroll
            for (int r = 0; r < 4; ++r) oT[dt][r] = 0.f;
    };

    // process the current staged pair: group's 32-key block kbg
    auto process = [&](int i, int itN, int myq, int cur) {
        const int kbg = 2 * i + grpW;
        const bool diag = (i == itN - 1);
        const bf16* kbase = &Kf[cur][0] + grpW * 4096;
        const bf16* vbase = &Vf[cur][0] + grpW * 4096;

        f32x4 st[2];
        __builtin_amdgcn_s_setprio(1);
#pragma unroll
        for (int nt = 0; nt < 2; ++nt) {
            f32x4 acc = {};
#pragma unroll
            for (int ks = 0; ks < 4; ++ks) {
                bf16x8 ak = *(const bf16x8*)(kbase + (nt * 4 + ks) * 512 + lane * 8);
                acc = __builtin_amdgcn_mfma_f32_16x16x32_bf16(ak, bqw[ks], acc, 0, 0, 0);
            }
            st[nt] = acc;
        }
        __builtin_amdgcn_s_setprio(0);
        if (diag) {
#pragma unroll
            for (int nt = 0; nt < 2; ++nt) {
                int kp0 = kbg * 32 + nt * 16 + quad * 4;
#pragma unroll
                for (int r = 0; r < 4; ++r)
                    if (kp0 + r > myq) st[nt][r] = NEG;
            }
        }

        float mx = st[0][0];
#pragma unroll
        for (int nt = 0; nt < 2; ++nt)
#pragma unroll
            for (int r = 0; r < 4; ++r) mx = fmaxf(mx, st[nt][r]);
        mx = fmaxf(mx, __shfl_xor(mx, 16, 64));
        mx = fmaxf(mx, __shfl_xor(mx, 32, 64));

        if (!__all(mx - m_i <= THR)) {
            float mnew = fmaxf(m_i, mx);
            float alpha = fast_exp2((m_i - mnew) * scl2);
            l_i *= alpha;
#pragma unroll
            for (int dt = 0; dt < 8; ++dt)
#pragma unroll
                for (int r = 0; r < 4; ++r) oT[dt][r] *= alpha;
            m_i = mnew;
        }
        float rs = 0.f;
#pragma unroll
        for (int nt = 0; nt < 2; ++nt)
#pragma unroll
            for (int r = 0; r < 4; ++r) {
                float p = fast_exp2((st[nt][r] - m_i) * scl2);
                st[nt][r] = p;
                rs += p;
            }
        rs += __shfl_xor(rs, 16, 64);
        rs += __shfl_xor(rs, 32, 64);
        l_i += rs;

        bf16x4 pf[2];
#pragma unroll
        for (int nt = 0; nt < 2; ++nt) {
            bf16x4 tt = {(bf16)st[nt][0], (bf16)st[nt][1],
                         (bf16)st[nt][2], (bf16)st[nt][3]};
            pf[nt] = tt;
        }

        __builtin_amdgcn_s_setprio(1);
#pragma unroll
        for (int nt = 0; nt < 2; ++nt)
#pragma unroll
            for (int dt = 0; dt < 8; ++dt) {
                bf16x4 av = *(const bf16x4*)(vbase + (nt * 8 + dt) * 256 + lane * 4);
                oT[dt] = mfma_16x16x16(av, pf[nt], oT[dt]);
            }
        __builtin_amdgcn_s_setprio(0);
    };

    // ---- tile 1: qt1, it1 = qt1+1 staged pairs --------------------------
    const int it1 = qt1 + 1;
    const int myq1 = qt1 * 64 + w4 * 16 + lrow;
    {
        const bf16* qrow = Q + ((long)(b * SEQ + myq1)) * (NH * HD) + h * HD;
#pragma unroll
        for (int ks = 0; ks < 4; ++ks)
            bqw[ks] = *(const bf16x8*)(qrow + ks * 32 + quad * 8);
    }
    stage(0, 0);
    __syncthreads();
#pragma unroll 1
    for (int i = 0; i < it1; ++i) {
        const int cur = i & 1;
        if (i + 1 < it1) stage(i + 1, cur ^ 1);
        process(i, it1, myq1, cur);
        __syncthreads();
    }
    combine_write_reset(myq1);

    // ---- tile 2: qt2, it2 = qt2+1 staged pairs --------------------------
    const int it2 = qt2 + 1;
    const int myq2 = qt2 * 64 + w4 * 16 + lrow;
    {
        const bf16* qrow = Q + ((long)(b * SEQ + myq2)) * (NH * HD) + h * HD;
#pragma unroll
        for (int ks = 0; ks < 4; ++ks)
            bqw[ks] = *(const bf16x8*)(qrow + ks * 32 + quad * 8);
    }
    stage(0, 0);
    __syncthreads();
#pragma unroll 1
    for (int i = 0; i < it2; ++i) {
        const int cur = i & 1;
        if (i + 1 < it2) stage(i + 1, cur ^ 1);
        process(i, it2, myq2, cur);
        __syncthreads();
    }
    combine_write_reset(myq2);
}

// ---------------------------------------------------------------------------
extern "C" void kernel_launch(void* const* d_in, const int* in_sizes, int n_in,
                              void* d_out, int out_size, void* d_ws, size_t ws_size,
                              hipStream_t stream) {
    const float* q_stream  = (const float*)d_in[0];
    const float* kv_stream = (const float*)d_in[1];
    const float* wq  = (const float*)d_in[2];
    const float* wk  = (const float*)d_in[3];
    const float* wv  = (const float*)d_in[4];
    const float* wo  = (const float*)d_in[5];
    const float* qnw = (const float*)d_in[6];
    const float* knw = (const float*)d_in[7];
    float* out = (float*)d_out;

    // workspace (bf16 elems), total 30M elems = 60MB
    bf16* ws   = (bf16*)d_ws;
    bf16* sb   = ws;                        // 8M: q bf16, later attn out
    bf16* wqT  = ws + 8L * 1024 * 1024;     // 4M: wq^T, later wo^T
    bf16* wkvT = wqT + 4L * 1024 * 1024;    // 2M: [wk^T ; wv^T] = [1024][2048]
    bf16* xq   = wkvT + 2L * 1024 * 1024;   // 8M: [4096][2048]
    bf16* xkv  = xq + 8L * 1024 * 1024;     // 4M: [4096][1024] = [K | V]
    bf16* kf   = xkv + 4L * 1024 * 1024;    // 2M: K fragment-major
    bf16* vf   = kf + 2L * 1024 * 1024;     // 2M: V^T fragment-major
    // kv bf16 staging lives in d_out (32 MB f32 >= 16 MB needed); the final
    // GEMM fully overwrites out, so scratch use is safe.
    bf16* sbKV = (bf16*)d_out;

    dim3 tb(32, 8);
    cvt_both<<<8192, 256, 0, stream>>>(q_stream, kv_stream, sb, sbKV);
    transpose_merged<<<dim3(64, 64, 2), tb, 0, stream>>>(wq, wk, wv, wqT, wkvT);
    gemm_bt<bf16><<<dim3(16, 32), 256, 0, stream>>>(sb, wqT, xq, 4096, 2048, 2048);
    transpose2d<<<dim3(64, 64), tb, 0, stream>>>(wo, wqT, 2048, 2048);
    gemm_bt<bf16><<<dim3(8, 32), 256, 0, stream>>>(sbKV, wkvT, xkv, 4096, 1024, 2048);
    rmsnorm_merged<<<20480, 256, 0, stream>>>(xq, xkv, qnw, knw);
    repack_merged<<<dim3(32, 4, 2), 256, 0, stream>>>(xkv, kf, vf);
    attn_kernel<<<dim3(512), dim3(512), 0, stream>>>(xq, kf, vf, sb);
    gemm_bt<float><<<dim3(16, 32), 256, 0, stream>>>(sb, wqT, out, 4096, 2048, 2048);

    (void)in_sizes; (void)n_in; (void)out_size; (void)ws_size;
}

// Round 12
// 352.834 us; speedup vs baseline: 1.1036x; 1.0699x over previous
//
#include <hip/hip_runtime.h>
#include <cstdint>

// ---------------------------------------------------------------------------
// JanusCrossAttention: B=2,S=2048, Q_DIM=KV_DIM=2048, H=16, D=128, KVH=4
// I/O fp32; internals bf16 MFMA, fp32 accumulate.
// R12: fuse gemm1 (xq) + gemm2 (xkv) into ONE 768-block launch -> exactly
// 3 blocks/CU, all co-resident, identical per-block work (same K, same 128^2
// tile). Rationale: R9-R11 established the m97-structure GEMM needs >=3
// blocks/CU for its implicit cross-block MFMA/staging overlap (m114); our
// separate 512/256-block grids gave 2/1 and ~330 TF effective (m102's
// N=2048 degradation). Launches 9 -> 8. Attn: R6 FROZEN (69.9 us).
// ---------------------------------------------------------------------------

using bf16 = __bf16;
using bf16x4 = __attribute__((ext_vector_type(4))) __bf16;
using bf16x8 = __attribute__((ext_vector_type(8))) __bf16;
using s16x4  = __attribute__((ext_vector_type(4))) short;
using f32x4  = __attribute__((ext_vector_type(4))) float;

#define SEQ 2048
#define NH 16
#define NKVH 4
#define HD 128

// finite "minus infinity": avoids inf-inf NaNs in the split-K defer-max path
#define NEG (-3.0e38f)

// 16x16x16 bf16 MFMA (K=16) — C layout of a prior 16x16 MFMA feeds B directly.
#if defined(__has_builtin)
#if __has_builtin(__builtin_amdgcn_mfma_f32_16x16x16bf16_1k)
#define HAVE_1K 1
#endif
#endif
__device__ __forceinline__ f32x4 mfma_16x16x16(bf16x4 a, bf16x4 b, f32x4 c) {
#ifdef HAVE_1K
    return __builtin_amdgcn_mfma_f32_16x16x16bf16_1k(
        __builtin_bit_cast(s16x4, a), __builtin_bit_cast(s16x4, b), c, 0, 0, 0);
#else
    f32x4 d;
    asm volatile("v_mfma_f32_16x16x16_bf16 %0, %1, %2, %3"
                 : "=v"(d) : "v"(a), "v"(b), "v"(c));
    return d;
#endif
}

// native exp2 (v_exp_f32)
__device__ __forceinline__ float fast_exp2(float x) {
#if defined(__has_builtin)
#if __has_builtin(__builtin_amdgcn_exp2f)
    return __builtin_amdgcn_exp2f(x);
#else
    return exp2f(x);
#endif
#else
    return exp2f(x);
#endif
}

// async global->LDS, 16B per lane. LDS dest must be wave-uniform base + lane*16.
__device__ __forceinline__ void load_lds16(const bf16* g, bf16* l) {
    __builtin_amdgcn_global_load_lds(
        (const __attribute__((address_space(1))) unsigned int*)g,
        (__attribute__((address_space(3))) unsigned int*)l, 16, 0, 0);
}

// ---------------------------------------------------------------------------
// fused cvt: q_stream -> oq (bf16), kv_stream -> okv (bf16).
__global__ __launch_bounds__(256) void cvt_both(const float* __restrict__ q,
                                                const float* __restrict__ kv,
                                                bf16* __restrict__ oq,
                                                bf16* __restrict__ okv) {
    int i = blockIdx.x * 256 + threadIdx.x;
    const float* in;
    bf16* out;
    int j;
    if (i < 1048576) { in = q;  out = oq;  j = i; }
    else             { in = kv; out = okv; j = i - 1048576; }
    const float4* p = (const float4*)in + (long)j * 2;
    float4 f0 = p[0], f1 = p[1];
    bf16x8 o = {(bf16)f0.x, (bf16)f0.y, (bf16)f0.z, (bf16)f0.w,
                (bf16)f1.x, (bf16)f1.y, (bf16)f1.z, (bf16)f1.w};
    *((bf16x8*)out + j) = o;
}

// 2D transpose + cast core: in fp32 [R][C] -> out bf16 [C][R]
__device__ __forceinline__ void transpose_body(const float* in, bf16* out,
                                               int R, int C, int bx, int by) {
    __shared__ bf16 tile[32][33];
    int x  = bx * 32 + threadIdx.x;
    int y0 = by * 32 + threadIdx.y;
#pragma unroll
    for (int i = 0; i < 32; i += 8) {
        int y = y0 + i;
        if (y < R && x < C) tile[threadIdx.y + i][threadIdx.x] = (bf16)in[(long)y * C + x];
    }
    __syncthreads();
    int ox  = by * 32 + threadIdx.x;
    int oy0 = bx * 32 + threadIdx.y;
#pragma unroll
    for (int i = 0; i < 32; i += 8) {
        int oy = oy0 + i;
        if (oy < C && ox < R) out[(long)oy * R + ox] = tile[threadIdx.x][threadIdx.y + i];
    }
}

// single-matrix transpose (used for wo after the fused GEMM releases wqT)
__global__ void transpose2d(const float* __restrict__ in, bf16* __restrict__ out,
                            int R, int C) {
    transpose_body(in, out, R, C, blockIdx.x, blockIdx.y);
}

// fused transpose: z=0 -> wq (2048x2048); z=1,x<16 -> wk, 16<=x<32 -> wv
// (each 2048x512, packed into wkvT = [wk^T ; wv^T]).
__global__ void transpose_merged(const float* __restrict__ wq,
                                 const float* __restrict__ wk,
                                 const float* __restrict__ wv,
                                 bf16* __restrict__ wqT,
                                 bf16* __restrict__ wkvT) {
    if (blockIdx.z == 0) {
        transpose_body(wq, wqT, 2048, 2048, blockIdx.x, blockIdx.y);
    } else {
        int x = blockIdx.x;
        if (x >= 32) return;
        if (x < 16) transpose_body(wk, wkvT, 2048, 512, x, blockIdx.y);
        else        transpose_body(wv, wkvT + 512L * 2048, 2048, 512, x - 16, blockIdx.y);
    }
}

// ---------------------------------------------------------------------------
// Shared GEMM block body: C128x128 tile at (m0,n0), A[MxK] @ BT[NxK]^T,
// bf16 in, fp32 acc, CT out. Double-buffered global_load_lds staging
// (R9 config — measured best).
template <typename CT>
__device__ __forceinline__ void gemm_block(const bf16* A, const bf16* BT, CT* C,
                                           int N, int K, int m0, int n0,
                                           bf16 (*As)[128][32], bf16 (*Bs)[128][32]) {
    const int tid  = threadIdx.x;
    const int wave = tid >> 6, lane = tid & 63;
    const int wm = (wave >> 1) * 64, wn = (wave & 1) * 64;
    const int lrow = lane & 15, quad = lane >> 4;
    const int lko = quad * 8;

    const bf16* ga0 = A  + (long)(m0 + (tid >> 2)) * K + (tid & 3) * 8;
    const bf16* ga1 = ga0 + 64L * K;
    const bf16* gb0 = BT + (long)(n0 + (tid >> 2)) * K + (tid & 3) * 8;
    const bf16* gb1 = gb0 + 64L * K;
    bf16* la0 = &As[0][0][0] + tid * 8;
    bf16* lb0 = &Bs[0][0][0] + tid * 8;

    f32x4 acc[4][4] = {};

    const int nIt = K >> 5;
    load_lds16(ga0, la0);
    load_lds16(ga1, la0 + 2048);
    load_lds16(gb0, lb0);
    load_lds16(gb1, lb0 + 2048);
    __syncthreads();

#pragma unroll 1
    for (int it = 0; it < nIt; ++it) {
        const int cur = it & 1;
        if (it + 1 < nIt) {
            const int k0 = (it + 1) * 32;
            bf16* la = la0 + (cur ^ 1) * 4096;
            bf16* lb = lb0 + (cur ^ 1) * 4096;
            load_lds16(ga0 + k0, la);
            load_lds16(ga1 + k0, la + 2048);
            load_lds16(gb0 + k0, lb);
            load_lds16(gb1 + k0, lb + 2048);
        }
        bf16x8 af[4], bfr[4];
#pragma unroll
        for (int i = 0; i < 4; ++i) af[i]  = *(const bf16x8*)(&As[cur][wm + i * 16 + lrow][lko]);
#pragma unroll
        for (int j = 0; j < 4; ++j) bfr[j] = *(const bf16x8*)(&Bs[cur][wn + j * 16 + lrow][lko]);
#pragma unroll
        for (int i = 0; i < 4; ++i)
#pragma unroll
            for (int j = 0; j < 4; ++j)
                acc[i][j] = __builtin_amdgcn_mfma_f32_16x16x32_bf16(af[i], bfr[j], acc[i][j], 0, 0, 0);
        __syncthreads();
    }
#pragma unroll
    for (int i = 0; i < 4; ++i) {
        int mrow0 = m0 + wm + i * 16 + quad * 4;
#pragma unroll
        for (int j = 0; j < 4; ++j) {
            int ncol = n0 + wn + j * 16 + lrow;
#pragma unroll
            for (int r = 0; r < 4; ++r)
                C[(long)(mrow0 + r) * N + ncol] = (CT)acc[i][j][r];
        }
    }
}

// standalone GEMM (gemm3: out = ao @ woT). XCD swizzle within grid.
template <typename CT>
__global__ __launch_bounds__(256) void gemm_bt(const bf16* __restrict__ A,
                                               const bf16* __restrict__ BT,
                                               CT* __restrict__ C,
                                               int M, int N, int K) {
    __shared__ bf16 As[2][128][32];
    __shared__ bf16 Bs[2][128][32];
    const int nwg = gridDim.x * gridDim.y;
    const int bid = blockIdx.y * gridDim.x + blockIdx.x;
    const int swz = (bid & 7) * (nwg >> 3) + (bid >> 3);
    const int bx = swz % gridDim.x, by = swz / gridDim.x;
    gemm_block<CT>(A, BT, C, N, K, by * 128, bx * 128, As, Bs);
}

// Fused gemm1+gemm2: blocks 0..511 -> xq = sb @ wqT^T (N=2048, gx=16);
// blocks 512..767 -> xkv = sbKV @ wkvT^T (N=1024, gx=8). Same K=2048, same
// tile -> identical per-block work; 768 blocks = exactly 3/CU, co-resident.
// Per-sub-grid XCD swizzle (sub%8 == global bid%8 since 512%8==0).
__global__ __launch_bounds__(256) void gemm12(const bf16* __restrict__ A1,
                                              const bf16* __restrict__ B1,
                                              bf16* __restrict__ C1,
                                              const bf16* __restrict__ A2,
                                              const bf16* __restrict__ B2,
                                              bf16* __restrict__ C2) {
    __shared__ bf16 As[2][128][32];
    __shared__ bf16 Bs[2][128][32];
    const int bid = blockIdx.x;
    const bf16 *A, *BT;
    bf16* C;
    int N, gx, sub, nsub;
    if (bid < 512) { A = A1; BT = B1; C = C1; N = 2048; gx = 16; sub = bid;       nsub = 512; }
    else           { A = A2; BT = B2; C = C2; N = 1024; gx = 8;  sub = bid - 512; nsub = 256; }
    const int swz = (sub & 7) * (nsub >> 3) + (sub >> 3);
    const int bx = swz % gx, by = swz / gx;
    gemm_block<bf16>(A, BT, C, N, 2048, by * 128, bx * 128, As, Bs);
}

// ---------------------------------------------------------------------------
// Fused per-head RMSNorm for xq (65536 vecs) and xkv K-half (16384 vecs).
__global__ __launch_bounds__(256) void rmsnorm_merged(bf16* __restrict__ XQ,
                                                      bf16* __restrict__ XKV,
                                                      const float* __restrict__ QW,
                                                      const float* __restrict__ KW) {
    int v = blockIdx.x * 4 + (threadIdx.x >> 6);
    int lane = threadIdx.x & 63;
    bf16* X; const float* W; int lhpr, stride, vv;
    if (v < 65536) { X = XQ;  W = QW; lhpr = 4; stride = 2048; vv = v; }
    else           { X = XKV; W = KW; lhpr = 2; stride = 1024; vv = v - 65536; }
    int row = vv >> lhpr, head = vv & ((1 << lhpr) - 1);
    bf16* x = X + (long)row * stride + head * HD;
    float fa = (float)x[lane * 2], fb = (float)x[lane * 2 + 1];
    float ss = fa * fa + fb * fb;
#pragma unroll
    for (int off = 1; off < 64; off <<= 1) ss += __shfl_xor(ss, off, 64);
    float r = rsqrtf(ss * (1.0f / 128.0f) + 1e-5f);
    x[lane * 2]     = (bf16)(fa * r * W[lane * 2]);
    x[lane * 2 + 1] = (bf16)(fb * r * W[lane * 2 + 1]);
}

// ---------------------------------------------------------------------------
// Fused repack of K and V^T into MFMA-fragment-major tiles (one launch).
__global__ __launch_bounds__(256) void repack_merged(const bf16* __restrict__ xkv,
                                                     bf16* __restrict__ kf,
                                                     bf16* __restrict__ vf) {
    __shared__ bf16 Vls[64][136];
    int kt = blockIdx.x, kvh = blockIdx.y, b = blockIdx.z;
    int tid = threadIdx.x, lane = tid & 63;
    int lrow = lane & 15, quad = lane >> 4;

    // ---- K part (no LDS) ----
    {
        int ks = tid >> 6;
        const bf16* src = xkv + ((long)b * SEQ + kt * 64) * 1024 + kvh * HD;
        bf16* dst = kf + ((long)((b * NKVH + kvh) * 32 + kt)) * 8192;
#pragma unroll
        for (int nt = 0; nt < 4; ++nt) {
            bf16x8 v = *(const bf16x8*)(src + (long)(nt * 16 + lrow) * 1024 + ks * 32 + quad * 8);
            *(bf16x8*)(dst + ((nt * 4 + ks) * 64 + lane) * 8) = v;
        }
    }

    // ---- V part (transpose via LDS) ----
    {
        const bf16* src = xkv + ((long)b * SEQ + kt * 64) * 1024 + 512 + kvh * HD;
#pragma unroll
        for (int p = 0; p < 4; ++p) {
            int c = p * 256 + tid;
            int r = c >> 4, dc = (c & 15) * 8;
            *(uint4*)(&Vls[r][dc]) = *(const uint4*)(src + (long)r * 1024 + dc);
        }
        __syncthreads();
        int w = tid >> 6;
        bf16* dst = vf + ((long)((b * NKVH + kvh) * 32 + kt)) * 8192;
#pragma unroll
        for (int nt = 0; nt < 4; ++nt)
#pragma unroll
            for (int dtl = 0; dtl < 2; ++dtl) {
                int dt = w * 2 + dtl;
                bf16x4 v = {Vls[nt * 16 + quad * 4 + 0][dt * 16 + lrow],
                            Vls[nt * 16 + quad * 4 + 1][dt * 16 + lrow],
                            Vls[nt * 16 + quad * 4 + 2][dt * 16 + lrow],
                            Vls[nt * 16 + quad * 4 + 3][dt * 16 + lrow]};
                *(bf16x4*)(dst + ((nt * 8 + dt) * 64 + lane) * 4) = v;
            }
    }
}

// ---------------------------------------------------------------------------
// Flash attention: R6 structure FROZEN (best measured: 69.9 us, VGPR 52).
__global__ __launch_bounds__(512, 4) void attn_kernel(const bf16* __restrict__ Q,
                                                      const bf16* __restrict__ KF,
                                                      const bf16* __restrict__ VF,
                                                      bf16* __restrict__ O) {
    __shared__ bf16 Kf[2][8192];   // [buf][half(2)·nt(2)·ks(4)·512] — 32 KB
    __shared__ bf16 Vf[2][8192];   // [buf][half(2)·nt(2)·dt(8)·256] — 32 KB
    const int tid = threadIdx.x, wave = tid >> 6, lane = tid & 63;
    const int w4 = wave & 3, grpW = wave >> 2;
    const int bid = blockIdx.x;
    const int grp = bid & 7;                  // -> XCD via bid%8 round-robin
    const int b = grp >> 2, kvh = grp & 3;
    const int slot = bid >> 3;                // 0..63
    const int pr = slot & 15;
    const int h = kvh * 4 + (slot >> 4);
    const int lrow = lane & 15, quad = lane >> 4;
    const float scl2 = 0.12751744f;     // (1/sqrt(128)) * log2(e)
    const float THR = 62.7f;            // ~8 ln-units in raw-score domain

    const int qt1 = 31 - pr, qt2 = pr;

    const bf16* kfb = KF + ((long)(b * NKVH + kvh) * 32) * 8192;
    const bf16* vfb = VF + ((long)(b * NKVH + kvh) * 32) * 8192;

    auto stage = [&](int pair, int bsel) {
        const bf16* kg = kfb + (long)pair * 8192 + tid * 8;
        const bf16* vg = vfb + (long)pair * 8192 + tid * 8;
        bf16* kd = &Kf[bsel][0] + tid * 8;
        bf16* vd = &Vf[bsel][0] + tid * 8;
        load_lds16(kg, kd);
        load_lds16(kg + 4096, kd + 4096);
        load_lds16(vg, vd);
        load_lds16(vg + 4096, vd + 4096);
    };

    float m_i = NEG, l_i = 0.f;
    f32x4 oT[8] = {};   // out^T: d = dt*16 + quad*4 + r, q = lane&15
    bf16x8 bqw[4];

    auto combine_write_reset = [&](int qrow) {
        float a1keep = 0.f;
        float* vs = (float*)&Vf[0][0];
        const int sl = w4 * 64 + lane;
        __syncthreads();
        if (grpW == 1) {
            float* d = vs + sl * 18;
#pragma unroll
            for (int dt = 0; dt < 4; ++dt)
#pragma unroll
                for (int r = 0; r < 4; ++r) d[dt * 4 + r] = oT[dt][r];
            d[16] = m_i; d[17] = l_i;
        }
        __syncthreads();
        if (grpW == 0) {
            const float* s = vs + sl * 18;
            float m1 = s[16], l1 = s[17];
            float ms = fmaxf(m_i, m1);
            float a0 = fast_exp2((m_i - ms) * scl2);
            float a1 = fast_exp2((m1 - ms) * scl2);
            a1keep = a1;
            l_i = a0 * l_i + a1 * l1;
#pragma unroll
            for (int dt = 0; dt < 4; ++dt)
#pragma unroll
                for (int r = 0; r < 4; ++r)
                    oT[dt][r] = a0 * oT[dt][r] + a1 * s[dt * 4 + r];
#pragma unroll
            for (int dt = 4; dt < 8; ++dt)
#pragma unroll
                for (int r = 0; r < 4; ++r) oT[dt][r] *= a0;
            m_i = ms;
        }
        __syncthreads();
        if (grpW == 1) {
            float* d = vs + sl * 16;
#pragma unroll
            for (int dt = 4; dt < 8; ++dt)
#pragma unroll
                for (int r = 0; r < 4; ++r) d[(dt - 4) * 4 + r] = oT[dt][r];
        }
        __syncthreads();
        if (grpW == 0) {
            const float* s = vs + sl * 16;
#pragma unroll
            for (int dt = 4; dt < 8; ++dt)
#pragma unroll
                for (int r = 0; r < 4; ++r) oT[dt][r] += a1keep * s[(dt - 4) * 4 + r];
            float inv_l = 1.0f / l_i;
            bf16* obase = O + ((long)(b * SEQ + qrow)) * (NH * HD) + h * HD;
#pragma unroll
            for (int dt = 0; dt < 8; ++dt) {
                bf16x4 o = {(bf16)(oT[dt][0] * inv_l), (bf16)(oT[dt][1] * inv_l),
                            (bf16)(oT[dt][2] * inv_l), (bf16)(oT[dt][3] * inv_l)};
                *(bf16x4*)(obase + dt * 16 + quad * 4) = o;
            }
        }
        __syncthreads();   // scratch/LDS free for restage
        m_i = NEG; l_i = 0.f;
#pragma unroll
        for (int dt = 0; dt < 8; ++dt)
#pragma unroll
            for (int r = 0; r < 4; ++r) oT[dt][r] = 0.f;
    };

    auto process = [&](int i, int itN, int myq, int cur) {
        const int kbg = 2 * i + grpW;
        const bool diag = (i == itN - 1);
        const bf16* kbase = &Kf[cur][0] + grpW * 4096;
        const bf16* vbase = &Vf[cur][0] + grpW * 4096;

        f32x4 st[2];
        __builtin_amdgcn_s_setprio(1);
#pragma unroll
        for (int nt = 0; nt < 2; ++nt) {
            f32x4 acc = {};
#pragma unroll
            for (int ks = 0; ks < 4; ++ks) {
                bf16x8 ak = *(const bf16x8*)(kbase + (nt * 4 + ks) * 512 + lane * 8);
                acc = __builtin_amdgcn_mfma_f32_16x16x32_bf16(ak, bqw[ks], acc, 0, 0, 0);
            }
            st[nt] = acc;
        }
        __builtin_amdgcn_s_setprio(0);
        if (diag) {
#pragma unroll
            for (int nt = 0; nt < 2; ++nt) {
                int kp0 = kbg * 32 + nt * 16 + quad * 4;
#pragma unroll
                for (int r = 0; r < 4; ++r)
                    if (kp0 + r > myq) st[nt][r] = NEG;
            }
        }

        float mx = st[0][0];
#pragma unroll
        for (int nt = 0; nt < 2; ++nt)
#pragma unroll
            for (int r = 0; r < 4; ++r) mx = fmaxf(mx, st[nt][r]);
        mx = fmaxf(mx, __shfl_xor(mx, 16, 64));
        mx = fmaxf(mx, __shfl_xor(mx, 32, 64));

        if (!__all(mx - m_i <= THR)) {
            float mnew = fmaxf(m_i, mx);
            float alpha = fast_exp2((m_i - mnew) * scl2);
            l_i *= alpha;
#pragma unroll
            for (int dt = 0; dt < 8; ++dt)
#pragma unroll
                for (int r = 0; r < 4; ++r) oT[dt][r] *= alpha;
            m_i = mnew;
        }
        float rs = 0.f;
#pragma unroll
        for (int nt = 0; nt < 2; ++nt)
#pragma unroll
            for (int r = 0; r < 4; ++r) {
                float p = fast_exp2((st[nt][r] - m_i) * scl2);
                st[nt][r] = p;
                rs += p;
            }
        rs += __shfl_xor(rs, 16, 64);
        rs += __shfl_xor(rs, 32, 64);
        l_i += rs;

        bf16x4 pf[2];
#pragma unroll
        for (int nt = 0; nt < 2; ++nt) {
            bf16x4 tt = {(bf16)st[nt][0], (bf16)st[nt][1],
                         (bf16)st[nt][2], (bf16)st[nt][3]};
            pf[nt] = tt;
        }

        __builtin_amdgcn_s_setprio(1);
#pragma unroll
        for (int nt = 0; nt < 2; ++nt)
#pragma unroll
            for (int dt = 0; dt < 8; ++dt) {
                bf16x4 av = *(const bf16x4*)(vbase + (nt * 8 + dt) * 256 + lane * 4);
                oT[dt] = mfma_16x16x16(av, pf[nt], oT[dt]);
            }
        __builtin_amdgcn_s_setprio(0);
    };

    // ---- tile 1: qt1, it1 = qt1+1 staged pairs --------------------------
    const int it1 = qt1 + 1;
    const int myq1 = qt1 * 64 + w4 * 16 + lrow;
    {
        const bf16* qrow = Q + ((long)(b * SEQ + myq1)) * (NH * HD) + h * HD;
#pragma unroll
        for (int ks = 0; ks < 4; ++ks)
            bqw[ks] = *(const bf16x8*)(qrow + ks * 32 + quad * 8);
    }
    stage(0, 0);
    __syncthreads();
#pragma unroll 1
    for (int i = 0; i < it1; ++i) {
        const int cur = i & 1;
        if (i + 1 < it1) stage(i + 1, cur ^ 1);
        process(i, it1, myq1, cur);
        __syncthreads();
    }
    combine_write_reset(myq1);

    // ---- tile 2: qt2, it2 = qt2+1 staged pairs --------------------------
    const int it2 = qt2 + 1;
    const int myq2 = qt2 * 64 + w4 * 16 + lrow;
    {
        const bf16* qrow = Q + ((long)(b * SEQ + myq2)) * (NH * HD) + h * HD;
#pragma unroll
        for (int ks = 0; ks < 4; ++ks)
            bqw[ks] = *(const bf16x8*)(qrow + ks * 32 + quad * 8);
    }
    stage(0, 0);
    __syncthreads();
#pragma unroll 1
    for (int i = 0; i < it2; ++i) {
        const int cur = i & 1;
        if (i + 1 < it2) stage(i + 1, cur ^ 1);
        process(i, it2, myq2, cur);
        __syncthreads();
    }
    combine_write_reset(myq2);
}

// ---------------------------------------------------------------------------
extern "C" void kernel_launch(void* const* d_in, const int* in_sizes, int n_in,
                              void* d_out, int out_size, void* d_ws, size_t ws_size,
                              hipStream_t stream) {
    const float* q_stream  = (const float*)d_in[0];
    const float* kv_stream = (const float*)d_in[1];
    const float* wq  = (const float*)d_in[2];
    const float* wk  = (const float*)d_in[3];
    const float* wv  = (const float*)d_in[4];
    const float* wo  = (const float*)d_in[5];
    const float* qnw = (const float*)d_in[6];
    const float* knw = (const float*)d_in[7];
    float* out = (float*)d_out;

    // workspace (bf16 elems), total 30M elems = 60MB
    bf16* ws   = (bf16*)d_ws;
    bf16* sb   = ws;                        // 8M: q bf16, later attn out
    bf16* wqT  = ws + 8L * 1024 * 1024;     // 4M: wq^T, later wo^T
    bf16* wkvT = wqT + 4L * 1024 * 1024;    // 2M: [wk^T ; wv^T] = [1024][2048]
    bf16* xq   = wkvT + 2L * 1024 * 1024;   // 8M: [4096][2048]
    bf16* xkv  = xq + 8L * 1024 * 1024;     // 4M: [4096][1024] = [K | V]
    bf16* kf   = xkv + 4L * 1024 * 1024;    // 2M: K fragment-major
    bf16* vf   = kf + 2L * 1024 * 1024;     // 2M: V^T fragment-major
    // kv bf16 staging lives in d_out (32 MB f32 >= 16 MB needed); the final
    // GEMM fully overwrites out, so scratch use is safe.
    bf16* sbKV = (bf16*)d_out;

    dim3 tb(32, 8);
    cvt_both<<<8192, 256, 0, stream>>>(q_stream, kv_stream, sb, sbKV);
    transpose_merged<<<dim3(64, 64, 2), tb, 0, stream>>>(wq, wk, wv, wqT, wkvT);
    gemm12<<<768, 256, 0, stream>>>(sb, wqT, xq, sbKV, wkvT, xkv);
    transpose2d<<<dim3(64, 64), tb, 0, stream>>>(wo, wqT, 2048, 2048);
    rmsnorm_merged<<<20480, 256, 0, stream>>>(xq, xkv, qnw, knw);
    repack_merged<<<dim3(32, 4, 2), 256, 0, stream>>>(xkv, kf, vf);
    attn_kernel<<<dim3(512), dim3(512), 0, stream>>>(xq, kf, vf, sb);
    gemm_bt<float><<<dim3(16, 32), 256, 0, stream>>>(sb, wqT, out, 4096, 2048, 2048);

    (void)in_sizes; (void)n_in; (void)out_size; (void)ws_size;
}

// Round 13
// 329.987 us; speedup vs baseline: 1.1801x; 1.0692x over previous
//
#include <hip/hip_runtime.h>
#include <cstdint>

// ---------------------------------------------------------------------------
// JanusCrossAttention: B=2,S=2048, Q_DIM=KV_DIM=2048, H=16, D=128, KVH=4
// I/O fp32; internals bf16 MFMA, fp32 accumulate.
// R13: launch collapse 8 -> 5 + RMSNorm fused into gemm12's epilogue.
//   1. cvt_trans: q/kv f32->bf16 + wq/wk/wv transposes, one launch
//   2. gemm12: xq and xkv in one 768-block launch (3 blocks/CU, R12-proven);
//      per-head RMSNorm applied to the fp32 accumulator in the epilogue
//      (each 128-col tile == one head; xkv cols>=512 are V, un-normed)
//   3. post_merged: wo transpose + K/V fragment repack, one launch
//   4. attn: R6 structure FROZEN (69.5 us, VGPR 52)
//   5. gemm3: out = ao @ woT (fp32 out)
// Rationale: R12 ledger puts the cheap pool at rmsnorm's 48 MB round-trip
// (~9 us) + 3 launch seams (~7 us). GEMM structure unchanged (R9-best).
// ---------------------------------------------------------------------------

using bf16 = __bf16;
using bf16x4 = __attribute__((ext_vector_type(4))) __bf16;
using bf16x8 = __attribute__((ext_vector_type(8))) __bf16;
using s16x4  = __attribute__((ext_vector_type(4))) short;
using f32x4  = __attribute__((ext_vector_type(4))) float;

#define SEQ 2048
#define NH 16
#define NKVH 4
#define HD 128

// finite "minus infinity": avoids inf-inf NaNs in the split-K defer-max path
#define NEG (-3.0e38f)

// 16x16x16 bf16 MFMA (K=16) — C layout of a prior 16x16 MFMA feeds B directly.
#if defined(__has_builtin)
#if __has_builtin(__builtin_amdgcn_mfma_f32_16x16x16bf16_1k)
#define HAVE_1K 1
#endif
#endif
__device__ __forceinline__ f32x4 mfma_16x16x16(bf16x4 a, bf16x4 b, f32x4 c) {
#ifdef HAVE_1K
    return __builtin_amdgcn_mfma_f32_16x16x16bf16_1k(
        __builtin_bit_cast(s16x4, a), __builtin_bit_cast(s16x4, b), c, 0, 0, 0);
#else
    f32x4 d;
    asm volatile("v_mfma_f32_16x16x16_bf16 %0, %1, %2, %3"
                 : "=v"(d) : "v"(a), "v"(b), "v"(c));
    return d;
#endif
}

// native exp2 (v_exp_f32)
__device__ __forceinline__ float fast_exp2(float x) {
#if defined(__has_builtin)
#if __has_builtin(__builtin_amdgcn_exp2f)
    return __builtin_amdgcn_exp2f(x);
#else
    return exp2f(x);
#endif
#else
    return exp2f(x);
#endif
}

// async global->LDS, 16B per lane. LDS dest must be wave-uniform base + lane*16.
__device__ __forceinline__ void load_lds16(const bf16* g, bf16* l) {
    __builtin_amdgcn_global_load_lds(
        (const __attribute__((address_space(1))) unsigned int*)g,
        (__attribute__((address_space(3))) unsigned int*)l, 16, 0, 0);
}

// ---------------------------------------------------------------------------
// flat-thread 32x32 transpose tile body: in fp32 [R][C] -> out bf16 [C][R]
__device__ __forceinline__ void transpose_flat(const float* in, bf16* out,
                                               int R, int C, int bx, int by) {
    __shared__ bf16 tile[32][33];
    int tx = threadIdx.x & 31, ty = threadIdx.x >> 5;
    int x  = bx * 32 + tx;
    int y0 = by * 32 + ty;
#pragma unroll
    for (int i = 0; i < 32; i += 8) {
        int y = y0 + i;
        if (y < R && x < C) tile[ty + i][tx] = (bf16)in[(long)y * C + x];
    }
    __syncthreads();
    int ox  = by * 32 + tx;
    int oy0 = bx * 32 + ty;
#pragma unroll
    for (int i = 0; i < 32; i += 8) {
        int oy = oy0 + i;
        if (oy < C && ox < R) out[(long)oy * R + ox] = tile[tx][ty + i];
    }
}

// fused: blocks 0..8191 cvt q/kv f32->bf16; 8192..12287 transpose wq;
// 12288..13311 wk; 13312..14335 wv.
__global__ __launch_bounds__(256) void cvt_trans(const float* __restrict__ q,
                                                 const float* __restrict__ kv,
                                                 bf16* __restrict__ oq,
                                                 bf16* __restrict__ okv,
                                                 const float* __restrict__ wq,
                                                 const float* __restrict__ wk,
                                                 const float* __restrict__ wv,
                                                 bf16* __restrict__ wqT,
                                                 bf16* __restrict__ wkvT) {
    int bid = blockIdx.x;
    if (bid < 8192) {
        int i = bid * 256 + threadIdx.x;
        const float* in;
        bf16* out;
        int j;
        if (i < 1048576) { in = q;  out = oq;  j = i; }
        else             { in = kv; out = okv; j = i - 1048576; }
        const float4* p = (const float4*)in + (long)j * 2;
        float4 f0 = p[0], f1 = p[1];
        bf16x8 o = {(bf16)f0.x, (bf16)f0.y, (bf16)f0.z, (bf16)f0.w,
                    (bf16)f1.x, (bf16)f1.y, (bf16)f1.z, (bf16)f1.w};
        *((bf16x8*)out + j) = o;
    } else if (bid < 12288) {
        int t = bid - 8192;
        transpose_flat(wq, wqT, 2048, 2048, t & 63, t >> 6);
    } else if (bid < 13312) {
        int t = bid - 12288;
        transpose_flat(wk, wkvT, 2048, 512, t & 15, t >> 4);
    } else {
        int t = bid - 13312;
        transpose_flat(wv, wkvT + 512L * 2048, 2048, 512, t & 15, t >> 4);
    }
}

// ---------------------------------------------------------------------------
// Shared GEMM block body: C 128x128 tile at (m0,n0), A[MxK] @ BT[NxK]^T,
// bf16 in, fp32 acc, CT out. Double-buffered global_load_lds staging
// (R9 config — measured best). If NORM: apply per-head RMSNorm to the fp32
// accumulator before the store — valid because each 128-col tile is exactly
// one head (n0 % 128 == 0); weight index d = wn + j*16 + lrow. Row
// sum-of-squares: 4x shfl_xor within the 16 lanes sharing a row, then a
// 1 KB LDS exchange (As reused as scratch) across the 2 waves per row.
template <typename CT, bool NORM>
__device__ __forceinline__ void gemm_block(const bf16* A, const bf16* BT, CT* C,
                                           int N, int K, int m0, int n0,
                                           bf16 (*As)[128][32], bf16 (*Bs)[128][32],
                                           const float* Wn) {
    const int tid  = threadIdx.x;
    const int wave = tid >> 6, lane = tid & 63;
    const int wm = (wave >> 1) * 64, wn = (wave & 1) * 64;
    const int lrow = lane & 15, quad = lane >> 4;
    const int lko = quad * 8;

    const bf16* ga0 = A  + (long)(m0 + (tid >> 2)) * K + (tid & 3) * 8;
    const bf16* ga1 = ga0 + 64L * K;
    const bf16* gb0 = BT + (long)(n0 + (tid >> 2)) * K + (tid & 3) * 8;
    const bf16* gb1 = gb0 + 64L * K;
    bf16* la0 = &As[0][0][0] + tid * 8;
    bf16* lb0 = &Bs[0][0][0] + tid * 8;

    f32x4 acc[4][4] = {};

    const int nIt = K >> 5;
    load_lds16(ga0, la0);
    load_lds16(ga1, la0 + 2048);
    load_lds16(gb0, lb0);
    load_lds16(gb1, lb0 + 2048);
    __syncthreads();

#pragma unroll 1
    for (int it = 0; it < nIt; ++it) {
        const int cur = it & 1;
        if (it + 1 < nIt) {
            const int k0 = (it + 1) * 32;
            bf16* la = la0 + (cur ^ 1) * 4096;
            bf16* lb = lb0 + (cur ^ 1) * 4096;
            load_lds16(ga0 + k0, la);
            load_lds16(ga1 + k0, la + 2048);
            load_lds16(gb0 + k0, lb);
            load_lds16(gb1 + k0, lb + 2048);
        }
        bf16x8 af[4], bfr[4];
#pragma unroll
        for (int i = 0; i < 4; ++i) af[i]  = *(const bf16x8*)(&As[cur][wm + i * 16 + lrow][lko]);
#pragma unroll
        for (int j = 0; j < 4; ++j) bfr[j] = *(const bf16x8*)(&Bs[cur][wn + j * 16 + lrow][lko]);
#pragma unroll
        for (int i = 0; i < 4; ++i)
#pragma unroll
            for (int j = 0; j < 4; ++j)
                acc[i][j] = __builtin_amdgcn_mfma_f32_16x16x32_bf16(af[i], bfr[j], acc[i][j], 0, 0, 0);
        __syncthreads();
    }

    if constexpr (NORM) {
        float* ssb = (float*)&As[0][0][0];   // [2][128] f32 scratch (1 KB)
#pragma unroll
        for (int i = 0; i < 4; ++i)
#pragma unroll
            for (int r = 0; r < 4; ++r) {
                float p = 0.f;
#pragma unroll
                for (int j = 0; j < 4; ++j) p += acc[i][j][r] * acc[i][j][r];
                p += __shfl_xor(p, 1, 64);
                p += __shfl_xor(p, 2, 64);
                p += __shfl_xor(p, 4, 64);
                p += __shfl_xor(p, 8, 64);
                if (lrow == 0) ssb[(wave & 1) * 128 + wm + i * 16 + quad * 4 + r] = p;
            }
        __syncthreads();
        float wgt[4];
#pragma unroll
        for (int j = 0; j < 4; ++j) wgt[j] = Wn[wn + j * 16 + lrow];
#pragma unroll
        for (int i = 0; i < 4; ++i) {
            const int row0 = wm + i * 16 + quad * 4;
#pragma unroll
            for (int r = 0; r < 4; ++r) {
                float tot = ssb[row0 + r] + ssb[128 + row0 + r];
                float rsc = rsqrtf(tot * (1.0f / 128.0f) + 1e-5f);
#pragma unroll
                for (int j = 0; j < 4; ++j) acc[i][j][r] *= rsc * wgt[j];
            }
        }
    }

#pragma unroll
    for (int i = 0; i < 4; ++i) {
        int mrow0 = m0 + wm + i * 16 + quad * 4;
#pragma unroll
        for (int j = 0; j < 4; ++j) {
            int ncol = n0 + wn + j * 16 + lrow;
#pragma unroll
            for (int r = 0; r < 4; ++r)
                C[(long)(mrow0 + r) * N + ncol] = (CT)acc[i][j][r];
        }
    }
}

// standalone GEMM (gemm3: out = ao @ woT). XCD swizzle within grid.
template <typename CT>
__global__ __launch_bounds__(256) void gemm_bt(const bf16* __restrict__ A,
                                               const bf16* __restrict__ BT,
                                               CT* __restrict__ C,
                                               int M, int N, int K) {
    __shared__ bf16 As[2][128][32];
    __shared__ bf16 Bs[2][128][32];
    const int nwg = gridDim.x * gridDim.y;
    const int bid = blockIdx.y * gridDim.x + blockIdx.x;
    const int swz = (bid & 7) * (nwg >> 3) + (bid >> 3);
    const int bx = swz % gridDim.x, by = swz / gridDim.x;
    gemm_block<CT, false>(A, BT, C, N, K, by * 128, bx * 128, As, Bs, nullptr);
}

// Fused gemm1+gemm2 with in-epilogue RMSNorm.
// blocks 0..511: xq = sb @ wqT^T (N=2048), norm with qnw (all 16 heads);
// blocks 512..767: xkv = sbKV @ wkvT^T (N=1024): n0<512 -> K head, norm with
// knw; n0>=512 -> V, no norm. 768 blocks = exactly 3/CU, co-resident.
__global__ __launch_bounds__(256) void gemm12(const bf16* __restrict__ A1,
                                              const bf16* __restrict__ B1,
                                              bf16* __restrict__ C1,
                                              const bf16* __restrict__ A2,
                                              const bf16* __restrict__ B2,
                                              bf16* __restrict__ C2,
                                              const float* __restrict__ qnw,
                                              const float* __restrict__ knw) {
    __shared__ bf16 As[2][128][32];
    __shared__ bf16 Bs[2][128][32];
    const int bid = blockIdx.x;
    if (bid < 512) {
        const int swz = (bid & 7) * 64 + (bid >> 3);
        const int bx = swz % 16, by = swz / 16;
        gemm_block<bf16, true>(A1, B1, C1, 2048, 2048, by * 128, bx * 128, As, Bs, qnw);
    } else {
        const int sub = bid - 512;
        const int swz = (sub & 7) * 32 + (sub >> 3);
        const int bx = swz % 8, by = swz / 8;
        const int n0 = bx * 128;
        if (n0 < 512)
            gemm_block<bf16, true>(A2, B2, C2, 1024, 2048, by * 128, n0, As, Bs, knw);
        else
            gemm_block<bf16, false>(A2, B2, C2, 1024, 2048, by * 128, n0, As, Bs, nullptr);
    }
}

// ---------------------------------------------------------------------------
// post_merged: blocks 0..4095 transpose wo -> woT (into wqT buffer, free
// after gemm12); blocks 4096..4351 repack K and V^T (xkv already normed).
__global__ __launch_bounds__(256) void post_merged(const float* __restrict__ wo,
                                                   bf16* __restrict__ woT,
                                                   const bf16* __restrict__ xkv,
                                                   bf16* __restrict__ kf,
                                                   bf16* __restrict__ vf) {
    __shared__ bf16 Vls[64][136];
    int bid = blockIdx.x;
    if (bid < 4096) {
        transpose_flat(wo, woT, 2048, 2048, bid & 63, bid >> 6);
        return;
    }
    int rb = bid - 4096;               // 0..255
    int kt = rb & 31, kvh = (rb >> 5) & 3, b = rb >> 7;
    int tid = threadIdx.x, lane = tid & 63;
    int lrow = lane & 15, quad = lane >> 4;

    // ---- K part (no LDS) ----
    {
        int ks = tid >> 6;
        const bf16* src = xkv + ((long)b * SEQ + kt * 64) * 1024 + kvh * HD;
        bf16* dst = kf + ((long)((b * NKVH + kvh) * 32 + kt)) * 8192;
#pragma unroll
        for (int nt = 0; nt < 4; ++nt) {
            bf16x8 v = *(const bf16x8*)(src + (long)(nt * 16 + lrow) * 1024 + ks * 32 + quad * 8);
            *(bf16x8*)(dst + ((nt * 4 + ks) * 64 + lane) * 8) = v;
        }
    }

    // ---- V part (transpose via LDS) ----
    {
        const bf16* src = xkv + ((long)b * SEQ + kt * 64) * 1024 + 512 + kvh * HD;
#pragma unroll
        for (int p = 0; p < 4; ++p) {
            int c = p * 256 + tid;
            int r = c >> 4, dc = (c & 15) * 8;
            *(uint4*)(&Vls[r][dc]) = *(const uint4*)(src + (long)r * 1024 + dc);
        }
        __syncthreads();
        int w = tid >> 6;
        bf16* dst = vf + ((long)((b * NKVH + kvh) * 32 + kt)) * 8192;
#pragma unroll
        for (int nt = 0; nt < 4; ++nt)
#pragma unroll
            for (int dtl = 0; dtl < 2; ++dtl) {
                int dt = w * 2 + dtl;
                bf16x4 v = {Vls[nt * 16 + quad * 4 + 0][dt * 16 + lrow],
                            Vls[nt * 16 + quad * 4 + 1][dt * 16 + lrow],
                            Vls[nt * 16 + quad * 4 + 2][dt * 16 + lrow],
                            Vls[nt * 16 + quad * 4 + 3][dt * 16 + lrow]};
                *(bf16x4*)(dst + ((nt * 8 + dt) * 64 + lane) * 4) = v;
            }
    }
}

// ---------------------------------------------------------------------------
// Flash attention: R6 structure FROZEN (best measured: 69.5 us, VGPR 52).
__global__ __launch_bounds__(512, 4) void attn_kernel(const bf16* __restrict__ Q,
                                                      const bf16* __restrict__ KF,
                                                      const bf16* __restrict__ VF,
                                                      bf16* __restrict__ O) {
    __shared__ bf16 Kf[2][8192];   // [buf][half(2)·nt(2)·ks(4)·512] — 32 KB
    __shared__ bf16 Vf[2][8192];   // [buf][half(2)·nt(2)·dt(8)·256] — 32 KB
    const int tid = threadIdx.x, wave = tid >> 6, lane = tid & 63;
    const int w4 = wave & 3, grpW = wave >> 2;
    const int bid = blockIdx.x;
    const int grp = bid & 7;                  // -> XCD via bid%8 round-robin
    const int b = grp >> 2, kvh = grp & 3;
    const int slot = bid >> 3;                // 0..63
    const int pr = slot & 15;
    const int h = kvh * 4 + (slot >> 4);
    const int lrow = lane & 15, quad = lane >> 4;
    const float scl2 = 0.12751744f;     // (1/sqrt(128)) * log2(e)
    const float THR = 62.7f;            // ~8 ln-units in raw-score domain

    const int qt1 = 31 - pr, qt2 = pr;

    const bf16* kfb = KF + ((long)(b * NKVH + kvh) * 32) * 8192;
    const bf16* vfb = VF + ((long)(b * NKVH + kvh) * 32) * 8192;

    auto stage = [&](int pair, int bsel) {
        const bf16* kg = kfb + (long)pair * 8192 + tid * 8;
        const bf16* vg = vfb + (long)pair * 8192 + tid * 8;
        bf16* kd = &Kf[bsel][0] + tid * 8;
        bf16* vd = &Vf[bsel][0] + tid * 8;
        load_lds16(kg, kd);
        load_lds16(kg + 4096, kd + 4096);
        load_lds16(vg, vd);
        load_lds16(vg + 4096, vd + 4096);
    };

    float m_i = NEG, l_i = 0.f;
    f32x4 oT[8] = {};   // out^T: d = dt*16 + quad*4 + r, q = lane&15
    bf16x8 bqw[4];

    auto combine_write_reset = [&](int qrow) {
        float a1keep = 0.f;
        float* vs = (float*)&Vf[0][0];
        const int sl = w4 * 64 + lane;
        __syncthreads();
        if (grpW == 1) {
            float* d = vs + sl * 18;
#pragma unroll
            for (int dt = 0; dt < 4; ++dt)
#pragma unroll
                for (int r = 0; r < 4; ++r) d[dt * 4 + r] = oT[dt][r];
            d[16] = m_i; d[17] = l_i;
        }
        __syncthreads();
        if (grpW == 0) {
            const float* s = vs + sl * 18;
            float m1 = s[16], l1 = s[17];
            float ms = fmaxf(m_i, m1);
            float a0 = fast_exp2((m_i - ms) * scl2);
            float a1 = fast_exp2((m1 - ms) * scl2);
            a1keep = a1;
            l_i = a0 * l_i + a1 * l1;
#pragma unroll
            for (int dt = 0; dt < 4; ++dt)
#pragma unroll
                for (int r = 0; r < 4; ++r)
                    oT[dt][r] = a0 * oT[dt][r] + a1 * s[dt * 4 + r];
#pragma unroll
            for (int dt = 4; dt < 8; ++dt)
#pragma unroll
                for (int r = 0; r < 4; ++r) oT[dt][r] *= a0;
            m_i = ms;
        }
        __syncthreads();
        if (grpW == 1) {
            float* d = vs + sl * 16;
#pragma unroll
            for (int dt = 4; dt < 8; ++dt)
#pragma unroll
                for (int r = 0; r < 4; ++r) d[(dt - 4) * 4 + r] = oT[dt][r];
        }
        __syncthreads();
        if (grpW == 0) {
            const float* s = vs + sl * 16;
#pragma unroll
            for (int dt = 4; dt < 8; ++dt)
#pragma unroll
                for (int r = 0; r < 4; ++r) oT[dt][r] += a1keep * s[(dt - 4) * 4 + r];
            float inv_l = 1.0f / l_i;
            bf16* obase = O + ((long)(b * SEQ + qrow)) * (NH * HD) + h * HD;
#pragma unroll
            for (int dt = 0; dt < 8; ++dt) {
                bf16x4 o = {(bf16)(oT[dt][0] * inv_l), (bf16)(oT[dt][1] * inv_l),
                            (bf16)(oT[dt][2] * inv_l), (bf16)(oT[dt][3] * inv_l)};
                *(bf16x4*)(obase + dt * 16 + quad * 4) = o;
            }
        }
        __syncthreads();   // scratch/LDS free for restage
        m_i = NEG; l_i = 0.f;
#pragma unroll
        for (int dt = 0; dt < 8; ++dt)
#pragma unroll
            for (int r = 0; r < 4; ++r) oT[dt][r] = 0.f;
    };

    auto process = [&](int i, int itN, int myq, int cur) {
        const int kbg = 2 * i + grpW;
        const bool diag = (i == itN - 1);
        const bf16* kbase = &Kf[cur][0] + grpW * 4096;
        const bf16* vbase = &Vf[cur][0] + grpW * 4096;

        f32x4 st[2];
        __builtin_amdgcn_s_setprio(1);
#pragma unroll
        for (int nt = 0; nt < 2; ++nt) {
            f32x4 acc = {};
#pragma unroll
            for (int ks = 0; ks < 4; ++ks) {
                bf16x8 ak = *(const bf16x8*)(kbase + (nt * 4 + ks) * 512 + lane * 8);
                acc = __builtin_amdgcn_mfma_f32_16x16x32_bf16(ak, bqw[ks], acc, 0, 0, 0);
            }
            st[nt] = acc;
        }
        __builtin_amdgcn_s_setprio(0);
        if (diag) {
#pragma unroll
            for (int nt = 0; nt < 2; ++nt) {
                int kp0 = kbg * 32 + nt * 16 + quad * 4;
#pragma unroll
                for (int r = 0; r < 4; ++r)
                    if (kp0 + r > myq) st[nt][r] = NEG;
            }
        }

        float mx = st[0][0];
#pragma unroll
        for (int nt = 0; nt < 2; ++nt)
#pragma unroll
            for (int r = 0; r < 4; ++r) mx = fmaxf(mx, st[nt][r]);
        mx = fmaxf(mx, __shfl_xor(mx, 16, 64));
        mx = fmaxf(mx, __shfl_xor(mx, 32, 64));

        if (!__all(mx - m_i <= THR)) {
            float mnew = fmaxf(m_i, mx);
            float alpha = fast_exp2((m_i - mnew) * scl2);
            l_i *= alpha;
#pragma unroll
            for (int dt = 0; dt < 8; ++dt)
#pragma unroll
                for (int r = 0; r < 4; ++r) oT[dt][r] *= alpha;
            m_i = mnew;
        }
        float rs = 0.f;
#pragma unroll
        for (int nt = 0; nt < 2; ++nt)
#pragma unroll
            for (int r = 0; r < 4; ++r) {
                float p = fast_exp2((st[nt][r] - m_i) * scl2);
                st[nt][r] = p;
                rs += p;
            }
        rs += __shfl_xor(rs, 16, 64);
        rs += __shfl_xor(rs, 32, 64);
        l_i += rs;

        bf16x4 pf[2];
#pragma unroll
        for (int nt = 0; nt < 2; ++nt) {
            bf16x4 tt = {(bf16)st[nt][0], (bf16)st[nt][1],
                         (bf16)st[nt][2], (bf16)st[nt][3]};
            pf[nt] = tt;
        }

        __builtin_amdgcn_s_setprio(1);
#pragma unroll
        for (int nt = 0; nt < 2; ++nt)
#pragma unroll
            for (int dt = 0; dt < 8; ++dt) {
                bf16x4 av = *(const bf16x4*)(vbase + (nt * 8 + dt) * 256 + lane * 4);
                oT[dt] = mfma_16x16x16(av, pf[nt], oT[dt]);
            }
        __builtin_amdgcn_s_setprio(0);
    };

    // ---- tile 1: qt1, it1 = qt1+1 staged pairs --------------------------
    const int it1 = qt1 + 1;
    const int myq1 = qt1 * 64 + w4 * 16 + lrow;
    {
        const bf16* qrow = Q + ((long)(b * SEQ + myq1)) * (NH * HD) + h * HD;
#pragma unroll
        for (int ks = 0; ks < 4; ++ks)
            bqw[ks] = *(const bf16x8*)(qrow + ks * 32 + quad * 8);
    }
    stage(0, 0);
    __syncthreads();
#pragma unroll 1
    for (int i = 0; i < it1; ++i) {
        const int cur = i & 1;
        if (i + 1 < it1) stage(i + 1, cur ^ 1);
        process(i, it1, myq1, cur);
        __syncthreads();
    }
    combine_write_reset(myq1);

    // ---- tile 2: qt2, it2 = qt2+1 staged pairs --------------------------
    const int it2 = qt2 + 1;
    const int myq2 = qt2 * 64 + w4 * 16 + lrow;
    {
        const bf16* qrow = Q + ((long)(b * SEQ + myq2)) * (NH * HD) + h * HD;
#pragma unroll
        for (int ks = 0; ks < 4; ++ks)
            bqw[ks] = *(const bf16x8*)(qrow + ks * 32 + quad * 8);
    }
    stage(0, 0);
    __syncthreads();
#pragma unroll 1
    for (int i = 0; i < it2; ++i) {
        const int cur = i & 1;
        if (i + 1 < it2) stage(i + 1, cur ^ 1);
        process(i, it2, myq2, cur);
        __syncthreads();
    }
    combine_write_reset(myq2);
}

// ---------------------------------------------------------------------------
extern "C" void kernel_launch(void* const* d_in, const int* in_sizes, int n_in,
                              void* d_out, int out_size, void* d_ws, size_t ws_size,
                              hipStream_t stream) {
    const float* q_stream  = (const float*)d_in[0];
    const float* kv_stream = (const float*)d_in[1];
    const float* wq  = (const float*)d_in[2];
    const float* wk  = (const float*)d_in[3];
    const float* wv  = (const float*)d_in[4];
    const float* wo  = (const float*)d_in[5];
    const float* qnw = (const float*)d_in[6];
    const float* knw = (const float*)d_in[7];
    float* out = (float*)d_out;

    // workspace (bf16 elems), total 30M elems = 60MB
    bf16* ws   = (bf16*)d_ws;
    bf16* sb   = ws;                        // 8M: q bf16, later attn out
    bf16* wqT  = ws + 8L * 1024 * 1024;     // 4M: wq^T, later wo^T
    bf16* wkvT = wqT + 4L * 1024 * 1024;    // 2M: [wk^T ; wv^T] = [1024][2048]
    bf16* xq   = wkvT + 2L * 1024 * 1024;   // 8M: [4096][2048]
    bf16* xkv  = xq + 8L * 1024 * 1024;     // 4M: [4096][1024] = [K | V]
    bf16* kf   = xkv + 4L * 1024 * 1024;    // 2M: K fragment-major
    bf16* vf   = kf + 2L * 1024 * 1024;     // 2M: V^T fragment-major
    // kv bf16 staging lives in d_out (32 MB f32 >= 8 MB needed); the final
    // GEMM fully overwrites out, so scratch use is safe.
    bf16* sbKV = (bf16*)d_out;

    cvt_trans<<<14336, 256, 0, stream>>>(q_stream, kv_stream, sb, sbKV,
                                         wq, wk, wv, wqT, wkvT);
    gemm12<<<768, 256, 0, stream>>>(sb, wqT, xq, sbKV, wkvT, xkv, qnw, knw);
    post_merged<<<4352, 256, 0, stream>>>(wo, wqT, xkv, kf, vf);
    attn_kernel<<<dim3(512), dim3(512), 0, stream>>>(xq, kf, vf, sb);
    gemm_bt<float><<<dim3(16, 32), 256, 0, stream>>>(sb, wqT, out, 4096, 2048, 2048);

    (void)in_sizes; (void)n_in; (void)out_size; (void)ws_size;
}